// Round 4
// baseline (1028.429 us; speedup 1.0000x reference)
//
#include <hip/hip_runtime.h>
#include <cstdint>
#include <cstddef>

// Problem constants (B=1, S=65536, D=1024, P=512, E=3, C=2)
#define T_TOK 65536
#define DDIM  1024
#define PDIM  512

typedef __attribute__((ext_vector_type(8))) short          shortx8;
typedef __attribute__((ext_vector_type(8))) unsigned short ushortx8;
typedef __attribute__((ext_vector_type(4))) float          floatx4;

__device__ __forceinline__ unsigned short f2bf_rn(float x){
  unsigned int u = __float_as_uint(x);
  unsigned int r = u + 0x7FFFu + ((u >> 16) & 1u);
  return (unsigned short)(r >> 16);
}
__device__ __forceinline__ float bf2f(unsigned short h){
  return __uint_as_float(((unsigned int)h) << 16);
}
// fast tanh, NaN-safe
__device__ __forceinline__ float ftanh(float x){
  float ez = __expf(2.f * x);
  return 1.f - 2.f / (ez + 1.f);
}
// Swizzled LDS K-tile [128 rows][32 k] bf16, row stride 64 B.
// 16B block q (0..3) stored at q ^ ((row>>1)&3): b128 frag reads conflict-free.
__device__ __forceinline__ int lds_off(int row, int q){
  return row * 32 + ((q ^ ((row >> 1) & 3)) << 3);
}
// Swizzled C-staging tile [128 rows][128 cols] bf16 (32 KB), 16B-block xor.
__device__ __forceinline__ int cst(int row, int col){
  return row * 128 + ((((col >> 3) ^ (row & 15))) << 3) + (col & 7);
}

// ---------------------------------------------------------------------------
// prep: blocks 0..127: tiled transpose W_t1 (1024x512) -> split hi/lo bf16
//       [p][k]; blocks 128..191: transpose W_a1 (512x512) -> bf16 [n][k];
//       blocks 192+: zero the accumulator/histogram region (int4 stores).
// ---------------------------------------------------------------------------
__global__ void prep(const float* __restrict__ Wt1, const float* __restrict__ Wa1,
                     unsigned short* __restrict__ W1th, unsigned short* __restrict__ W1tl,
                     unsigned short* __restrict__ Wath, int* __restrict__ zbase)
{
  __shared__ float tile[64][65];
  const int b = blockIdx.x, tid = threadIdx.x;
  if (b < 128){
    const int k0 = (b >> 3) * 64, p0 = (b & 7) * 64;
    #pragma unroll
    for (int it = 0; it < 4; it++){
      int lin = it * 256 + tid;
      int r = lin >> 4, c = (lin & 15) << 2;
      float4 v = *(const float4*)(Wt1 + (size_t)(k0 + r) * PDIM + p0 + c);
      tile[r][c] = v.x; tile[r][c + 1] = v.y; tile[r][c + 2] = v.z; tile[r][c + 3] = v.w;
    }
    __syncthreads();
    #pragma unroll
    for (int it = 0; it < 4; it++){
      int lin = it * 256 + tid;
      int pr = lin >> 4, kc = (lin & 15) << 2;
      ushort4 h, l;
      float x0 = tile[kc][pr], x1 = tile[kc + 1][pr], x2 = tile[kc + 2][pr], x3 = tile[kc + 3][pr];
      h.x = f2bf_rn(x0); l.x = f2bf_rn(x0 - bf2f(h.x));
      h.y = f2bf_rn(x1); l.y = f2bf_rn(x1 - bf2f(h.y));
      h.z = f2bf_rn(x2); l.z = f2bf_rn(x2 - bf2f(h.z));
      h.w = f2bf_rn(x3); l.w = f2bf_rn(x3 - bf2f(h.w));
      size_t o = (size_t)(p0 + pr) * DDIM + k0 + kc;
      *(ushort4*)(W1th + o) = h;
      *(ushort4*)(W1tl + o) = l;
    }
  } else if (b < 192){
    const int bb = b - 128;
    const int k0 = (bb >> 3) * 64, n0 = (bb & 7) * 64;
    #pragma unroll
    for (int it = 0; it < 4; it++){
      int lin = it * 256 + tid;
      int r = lin >> 4, c = (lin & 15) << 2;
      float4 v = *(const float4*)(Wa1 + (size_t)(k0 + r) * PDIM + n0 + c);
      tile[r][c] = v.x; tile[r][c + 1] = v.y; tile[r][c + 2] = v.z; tile[r][c + 3] = v.w;
    }
    __syncthreads();
    #pragma unroll
    for (int it = 0; it < 4; it++){
      int lin = it * 256 + tid;
      int nr = lin >> 4, kc = (lin & 15) << 2;
      ushort4 h;
      h.x = f2bf_rn(tile[kc][nr]);
      h.y = f2bf_rn(tile[kc + 1][nr]);
      h.z = f2bf_rn(tile[kc + 2][nr]);
      h.w = f2bf_rn(tile[kc + 3][nr]);
      *(ushort4*)(Wath + (size_t)(n0 + nr) * PDIM + k0 + kc) = h;
    }
  } else {
    int idx = (b - 192) * 256 + tid;
    if (idx < 103440){
      int4 z; z.x = 0; z.y = 0; z.z = 0; z.w = 0;
      ((int4*)zbase)[idx] = z;
    }
  }
}

// ---------------------------------------------------------------------------
// gemm_main: patches = tanh(X @ W_t1), split-bf16 3-product (~fp32 accurate).
// 128x128 tile, BK=32, 256 threads. XCD-aware block remap. Epilogue: LDS
// C-staging -> coalesced nontemporal bf16 stores, bag column sums, fused
// gate GEMV partials -> atomicAdd glog[t][6].
// ---------------------------------------------------------------------------
__global__ __launch_bounds__(256, 4)
void gemm_main(const float* __restrict__ A,
               const unsigned short* __restrict__ Bhg,
               const unsigned short* __restrict__ Blg,
               unsigned short* __restrict__ Ptch,
               float* __restrict__ bagsum,
               float* __restrict__ glog,
               const float* __restrict__ Wg0,
               const float* __restrict__ Wg1,
               const float* __restrict__ Wg2)
{
  __shared__ __align__(16) unsigned short smem[16384];   // 32 KB
  unsigned short* Ah = smem;
  unsigned short* Al = smem + 4096;
  unsigned short* Bh = smem + 8192;
  unsigned short* Bl = smem + 12288;

  const int tid = threadIdx.x;
  // XCD-aware remap: L%8 -> XCD; same-y n-blocks on consecutive slots of one XCD
  const int L = blockIdx.y * 4 + blockIdx.x;
  const int g = L & 7, s = L >> 3;
  const int m0 = ((g << 6) | (s >> 2)) * 128;
  const int n0 = (s & 3) * 128;

  const int lane = tid & 63;
  const int wv   = tid >> 6;
  const int wm   = (wv & 1) << 6;
  const int wn   = (wv >> 1) << 6;
  const int lr   = lane & 15;
  const int quad = lane >> 4;

  // A staging addressing (coalesced 16B/lane)
  const int ar  = tid >> 3;               // 0..31
  const int akq = (tid & 7) << 2;         // element 0,4,..28
  const int aq  = akq >> 3;               // 16B block
  const int ak4 = akq & 7;                // 0 or 4
  const float* asrc = A + (size_t)(m0 + ar) * DDIM + akq;
  // B staging addressing
  const int br = tid >> 2;                // 0..63
  const int bq = tid & 3;
  const size_t boff0 = (size_t)(n0 + br) * DDIM + bq * 8;

  floatx4 acc[4][4];
  #pragma unroll
  for (int i = 0; i < 4; i++)
    #pragma unroll
    for (int j = 0; j < 4; j++)
      acc[i][j] = (floatx4){0.f, 0.f, 0.f, 0.f};

  for (int kb = 0; kb < 32; ++kb){
    const int k0 = kb << 5;
    // stage A: fp32 -> hi/lo bf16 (truncation split), coalesced float4 loads
    #pragma unroll
    for (int i = 0; i < 4; i++){
      const int row = ar + i * 32;
      float4 v = *(const float4*)(asrc + (size_t)i * 32 * DDIM + k0);
      unsigned int ux = __float_as_uint(v.x), uy = __float_as_uint(v.y);
      unsigned int uz = __float_as_uint(v.z), uw = __float_as_uint(v.w);
      float rx = v.x - __uint_as_float(ux & 0xFFFF0000u);
      float ry = v.y - __uint_as_float(uy & 0xFFFF0000u);
      float rz = v.z - __uint_as_float(uz & 0xFFFF0000u);
      float rw = v.w - __uint_as_float(uw & 0xFFFF0000u);
      ushort4 h, l;
      h.x = (unsigned short)(ux >> 16); l.x = (unsigned short)(__float_as_uint(rx) >> 16);
      h.y = (unsigned short)(uy >> 16); l.y = (unsigned short)(__float_as_uint(ry) >> 16);
      h.z = (unsigned short)(uz >> 16); l.z = (unsigned short)(__float_as_uint(rz) >> 16);
      h.w = (unsigned short)(uw >> 16); l.w = (unsigned short)(__float_as_uint(rw) >> 16);
      const int off = row * 32 + ((aq ^ ((row >> 1) & 3)) << 3) + ak4;
      *(ushort4*)&Ah[off] = h;
      *(ushort4*)&Al[off] = l;
    }
    // stage B (pre-split bf16 [n][k]), 16B/lane
    #pragma unroll
    for (int it = 0; it < 2; it++){
      const int row = br + it * 64;
      const size_t off = boff0 + (size_t)it * 64 * DDIM + k0;
      const int d = lds_off(row, bq);
      *(ushortx8*)&Bh[d] = *(const ushortx8*)(Bhg + off);
      *(ushortx8*)&Bl[d] = *(const ushortx8*)(Blg + off);
    }
    __syncthreads();
    shortx8 a0[4], a1[4], b0[4], b1[4];
    #pragma unroll
    for (int i = 0; i < 4; i++){
      a0[i] = *(const shortx8*)&Ah[lds_off(wm + i * 16 + lr, quad)];
      a1[i] = *(const shortx8*)&Al[lds_off(wm + i * 16 + lr, quad)];
      b0[i] = *(const shortx8*)&Bh[lds_off(wn + i * 16 + lr, quad)];
      b1[i] = *(const shortx8*)&Bl[lds_off(wn + i * 16 + lr, quad)];
    }
    #pragma unroll
    for (int i = 0; i < 4; i++){
      #pragma unroll
      for (int j = 0; j < 4; j++){
        acc[i][j] = __builtin_amdgcn_mfma_f32_16x16x32_bf16(a0[i], b0[j], acc[i][j], 0, 0, 0);
        acc[i][j] = __builtin_amdgcn_mfma_f32_16x16x32_bf16(a1[i], b0[j], acc[i][j], 0, 0, 0);
        acc[i][j] = __builtin_amdgcn_mfma_f32_16x16x32_bf16(a0[i], b1[j], acc[i][j], 0, 0, 0);
      }
    }
    __syncthreads();
  }

  // gate weights for this lane's 4 columns
  float wgr[4][6];
  #pragma unroll
  for (int j = 0; j < 4; j++){
    int c = n0 + wn + j * 16 + lr;
    wgr[j][0] = Wg0[c * 2]; wgr[j][1] = Wg0[c * 2 + 1];
    wgr[j][2] = Wg1[c * 2]; wgr[j][3] = Wg1[c * 2 + 1];
    wgr[j][4] = Wg2[c * 2]; wgr[j][5] = Wg2[c * 2 + 1];
  }

  // epilogue: tanh -> LDS C-tile (bf16) + bag sums + gate partials
  float csum[4] = {0.f, 0.f, 0.f, 0.f};
  #pragma unroll
  for (int i = 0; i < 4; i++){
    float gp[4][6];
    #pragma unroll
    for (int k = 0; k < 4; k++)
      #pragma unroll
      for (int gg = 0; gg < 6; gg++) gp[k][gg] = 0.f;
    const int r0 = wm + i * 16 + quad * 4;
    #pragma unroll
    for (int j = 0; j < 4; j++){
      float t0 = ftanh(acc[i][j][0]);
      float t1 = ftanh(acc[i][j][1]);
      float t2 = ftanh(acc[i][j][2]);
      float t3 = ftanh(acc[i][j][3]);
      const int col = wn + j * 16 + lr;
      smem[cst(r0 + 0, col)] = f2bf_rn(t0);
      smem[cst(r0 + 1, col)] = f2bf_rn(t1);
      smem[cst(r0 + 2, col)] = f2bf_rn(t2);
      smem[cst(r0 + 3, col)] = f2bf_rn(t3);
      csum[j] += t0 + t1 + t2 + t3;
      #pragma unroll
      for (int gg = 0; gg < 6; gg++){
        gp[0][gg] += t0 * wgr[j][gg];
        gp[1][gg] += t1 * wgr[j][gg];
        gp[2][gg] += t2 * wgr[j][gg];
        gp[3][gg] += t3 * wgr[j][gg];
      }
    }
    #pragma unroll
    for (int st = 1; st < 16; st <<= 1){
      #pragma unroll
      for (int k = 0; k < 4; k++)
        #pragma unroll
        for (int gg = 0; gg < 6; gg++)
          gp[k][gg] += __shfl_xor(gp[k][gg], st);
    }
    if (lr == 0){
      #pragma unroll
      for (int k = 0; k < 4; k++)
        #pragma unroll
        for (int gg = 0; gg < 6; gg++)
          atomicAdd(&glog[(size_t)(m0 + r0 + k) * 6 + gg], gp[k][gg]);
    }
  }
  __syncthreads();
  // coalesced nontemporal patch store: 16B/lane
  {
    const int row = tid >> 1, half = tid & 1;
    floatx4* gdst = (floatx4*)(Ptch + (size_t)(m0 + row) * PDIM + n0 + half * 64);
    const int rsw = row & 15;
    #pragma unroll
    for (int jj = 0; jj < 8; jj++){
      const int blk = half * 8 + jj;
      floatx4 v = *(floatx4*)&smem[row * 128 + ((blk ^ rsw) << 3)];
      __builtin_nontemporal_store(v, gdst + jj);
    }
  }
  // bag column sums
  #pragma unroll
  for (int j = 0; j < 4; j++){
    float sJ = csum[j];
    sJ += __shfl_xor(sJ, 16);
    sJ += __shfl_xor(sJ, 32);
    if (lane < 16) atomicAdd(&bagsum[n0 + wn + j * 16 + lane], sJ);
  }
}

// ---------------------------------------------------------------------------
// gates_small: from glog[t][6] compute router_logits out, masks, keys,
// counts, 4096-bin level-1 histograms.
// ---------------------------------------------------------------------------
__global__ void gates_small(const float* __restrict__ glog, float* __restrict__ dout,
                            unsigned int* __restrict__ wkey, unsigned char* __restrict__ mask3,
                            int* __restrict__ params, int* __restrict__ hist)
{
  __shared__ int lc[3];
  const int tid = threadIdx.x;
  if (tid < 3) lc[tid] = 0;
  __syncthreads();
  const int t = blockIdx.x * 256 + tid;
  float2 p0 = *(const float2*)(glog + (size_t)t * 6);
  float2 p1 = *(const float2*)(glog + (size_t)t * 6 + 2);
  float2 p2 = *(const float2*)(glog + (size_t)t * 6 + 4);
  dout[8 + 2 * t]     = p0.x;
  dout[8 + 2 * t + 1] = p0.y;
  int m0 = p0.y > p0.x;
  int m1 = p1.y > p1.x;
  int m2 = p2.y > p2.x;
  mask3[t] = (unsigned char)(m0 | (m1 << 1) | (m2 << 2));
  float d = fabsf(p0.x - p0.y);
  float w = 1.0f / (1.0f + __expf(-d));
  unsigned int u = __float_as_uint(w);
  u = u < 0x3F000000u ? 0x3F000000u : u;
  u = u > 0x3F7FFFFFu ? 0x3F7FFFFFu : u;
  wkey[t] = u;
  int b = (int)((u >> 11) & 0xFFFu);
  if (m0){ atomicAdd(&hist[b], 1);        atomicAdd(&lc[0], 1); }
  if (m1){ atomicAdd(&hist[4096 + b], 1); atomicAdd(&lc[1], 1); }
  if (m2){ atomicAdd(&hist[8192 + b], 1); atomicAdd(&lc[2], 1); }
  __syncthreads();
  if (tid < 3 && lc[tid]) atomicAdd(&params[tid], lc[tid]);
}

// ---------------------------------------------------------------------------
// find_bucket: nums via shifts; 12-bit bucket of nums-th largest (suffix scan)
// params: [0..2] cnt [3..5] nums [6..8] bucket [9..11] rank-in-bucket
//         [12..14] theta_u [15..17] r_ties [18..20] c_eq [21] compact count
// ---------------------------------------------------------------------------
__global__ void find_bucket(int* __restrict__ params, const int* __restrict__ hist)
{
  __shared__ int cs[256], orig[256];
  __shared__ int selc, selrk;
  const int tid = threadIdx.x;
  for (int e = 0; e < 3; e++){
    int cnt = params[e];
    int shift = (e == 1) ? 1 : 2;
    int nums = cnt >> shift;
    if (nums == 0) nums = cnt;
    if (tid == 0) params[3 + e] = nums;
    __syncthreads();
    if (nums == 0){
      if (tid == 0){ params[6 + e] = -1; params[9 + e] = 0; }
      __syncthreads();
      continue;
    }
    const int* h = hist + e * 4096 + tid * 16;
    int s = 0;
    #pragma unroll
    for (int j = 0; j < 16; j++) s += h[j];
    cs[tid] = s; orig[tid] = s;
    __syncthreads();
    for (int off = 1; off < 256; off <<= 1){
      int v = (tid + off < 256) ? cs[tid + off] : 0;
      __syncthreads();
      cs[tid] += v;
      __syncthreads();
    }
    if (cs[tid] >= nums && (cs[tid] - orig[tid]) < nums){
      selc = tid; selrk = nums - (cs[tid] - orig[tid]);
    }
    __syncthreads();
    if (tid == 0){
      int ch = selc, rk = selrk;
      const int* hh = hist + e * 4096 + ch * 16;
      int acc = 0;
      for (int j = 15; j >= 0; j--){
        int c = hh[j];
        if (acc + c >= rk){ params[6 + e] = ch * 16 + j; params[9 + e] = rk - acc; break; }
        acc += c;
      }
    }
    __syncthreads();
  }
}

// ---------------------------------------------------------------------------
// level2hist: 2048-bin histogram (mantissa bits [10:0]) within chosen bucket.
// ---------------------------------------------------------------------------
__global__ void level2hist(const int* __restrict__ params, const unsigned int* __restrict__ wkey,
                           const unsigned char* __restrict__ mask3, int* __restrict__ h2)
{
  const int e = blockIdx.y;
  const int B = params[6 + e];
  if (B < 0) return;
  const unsigned char bit = (unsigned char)(1u << e);
  const int t0 = blockIdx.x * 2048 + threadIdx.x;
  #pragma unroll
  for (int i = 0; i < 8; i++){
    int t = t0 + i * 256;
    if (mask3[t] & bit){
      unsigned int u = wkey[t];
      if ((int)((u >> 11) & 0xFFFu) == B) atomicAdd(&h2[e * 2048 + (u & 2047u)], 1);
    }
  }
}

// ---------------------------------------------------------------------------
// find_theta: exact 23-bit threshold key, ties-to-take r, tie count c_eq.
// ---------------------------------------------------------------------------
__global__ void find_theta(int* __restrict__ params, const int* __restrict__ h2)
{
  const int e = blockIdx.x;
  const int tid = threadIdx.x;
  __shared__ int cs[256], orig[256];
  __shared__ int selc;
  int B = params[6 + e], rank = params[9 + e];
  if (B < 0){
    if (tid == 0){ params[12 + e] = (int)0xFFFFFFFFu; params[15 + e] = 0; params[18 + e] = 0; }
    return;
  }
  const int* h = h2 + e * 2048 + tid * 8;
  int s = 0;
  #pragma unroll
  for (int j = 0; j < 8; j++) s += h[j];
  cs[tid] = s; orig[tid] = s;
  __syncthreads();
  for (int off = 1; off < 256; off <<= 1){
    int v = (tid + off < 256) ? cs[tid + off] : 0;
    __syncthreads();
    cs[tid] += v;
    __syncthreads();
  }
  if (cs[tid] >= rank && (cs[tid] - orig[tid]) < rank) selc = tid;
  __syncthreads();
  if (tid == 0){
    int ch = selc;
    int rk = rank - (cs[ch] - orig[ch]);
    const int* hh = h2 + e * 2048 + ch * 8;
    int acc = 0;
    for (int j = 7; j >= 0; j--){
      int c = hh[j];
      if (acc + c >= rk){
        int sub = ch * 8 + j;
        params[12 + e] = (int)(0x3F000000u | ((unsigned)B << 11) | (unsigned)sub);
        params[15 + e] = rk - acc;
        params[18 + e] = c;
        break;
      }
      acc += c;
    }
  }
}

// ---------------------------------------------------------------------------
// mark_sel: fast parallel path when all ties taken; stable scan otherwise.
// ---------------------------------------------------------------------------
__global__ void mark_sel(const int* __restrict__ params, const unsigned int* __restrict__ wkey,
                         const unsigned char* __restrict__ mask3, unsigned char* __restrict__ selb)
{
  const int e = blockIdx.y;
  const int bx = blockIdx.x;
  const int tid = threadIdx.x;
  const unsigned int theta = (unsigned int)params[12 + e];
  const int r = params[15 + e];
  const int ceq = params[18 + e];
  const unsigned char bit = (unsigned char)(1u << e);
  unsigned char* sb = selb + e * T_TOK;
  if (ceq == r){
    int t0 = bx * 2048;
    #pragma unroll
    for (int i = 0; i < 8; i++){
      int t = t0 + i * 256 + tid;
      unsigned char mk = mask3[t] & bit;
      sb[t] = (mk && wkey[t] >= theta) ? 1 : 0;
    }
  } else {
    if (bx) return;
    __shared__ int basec;
    __shared__ int wsum[4];
    if (tid == 0) basec = 0;
    __syncthreads();
    const int lane = tid & 63, w = tid >> 6;
    for (int c = 0; c < 256; c++){
      int t = c * 256 + tid;
      unsigned char mk = mask3[t] & bit;
      unsigned int u = mk ? wkey[t] : 0u;
      bool gt = mk && (u > theta);
      bool eq = mk && (u == theta);
      unsigned long long bal = __ballot(eq);
      if (lane == 0) wsum[w] = __popcll(bal);
      __syncthreads();
      int wbase = 0;
      for (int ww = 0; ww < w; ww++) wbase += wsum[ww];
      int pos = basec + wbase + __popcll(bal & ((1ull << lane) - 1ull));
      sb[t] = (gt || (eq && pos < r)) ? 1 : 0;
      __syncthreads();
      if (tid == 0) basec += wsum[0] + wsum[1] + wsum[2] + wsum[3];
      __syncthreads();
    }
  }
}

// ---------------------------------------------------------------------------
// compact: tokens with total_sel>0 + multiplicity weight; count in params[21].
// ---------------------------------------------------------------------------
__global__ void compact(const unsigned char* __restrict__ selb, int* __restrict__ cidx,
                        float* __restrict__ wgt, int* __restrict__ params)
{
  int t = blockIdx.x * 256 + threadIdx.x;
  int ts = selb[t] + selb[T_TOK + t] + selb[2 * T_TOK + t];
  int lane = threadIdx.x & 63;
  unsigned long long bal = __ballot(ts > 0);
  int base = 0;
  if (lane == 0) base = atomicAdd(&params[21], __popcll(bal));
  base = __shfl(base, 0);
  if (ts){
    int pos = base + __popcll(bal & ((1ull << lane) - 1ull));
    cidx[pos] = t;
    wgt[pos] = (float)ts;
  }
}

// ---------------------------------------------------------------------------
// meanfeat_c: column sums of (bf16) patches over sel0/sel1 rows, via the
// compacted union list.
// ---------------------------------------------------------------------------
__global__ void meanfeat_c(const unsigned short* __restrict__ Ptch,
                           const unsigned char* __restrict__ selb,
                           const int* __restrict__ cidx, const int* __restrict__ params,
                           float* __restrict__ mf)
{
  const int count = params[21];
  const int base = blockIdx.x * 256;
  if (base >= count) return;
  const int n = min(256, count - base);
  const int tid = threadIdx.x;
  __shared__ int cl[256];
  __shared__ unsigned char f0s[256], f1s[256];
  if (tid < n){
    int c = cidx[base + tid];
    cl[tid] = c;
    f0s[tid] = selb[c];
    f1s[tid] = selb[T_TOK + c];
  }
  __syncthreads();
  float s00 = 0, s01 = 0, s10 = 0, s11 = 0;
  for (int i = 0; i < n; i++){
    int f0 = f0s[i], f1 = f1s[i];
    if (f0 | f1){
      unsigned int u = *(const unsigned int*)(Ptch + (size_t)cl[i] * PDIM + tid * 2);
      float vx = bf2f((unsigned short)(u & 0xFFFFu));
      float vy = bf2f((unsigned short)(u >> 16));
      if (f0){ s00 += vx; s01 += vy; }
      if (f1){ s10 += vx; s11 += vy; }
    }
  }
  atomicAdd(&mf[tid * 2],           s00);
  atomicAdd(&mf[tid * 2 + 1],       s01);
  atomicAdd(&mf[512 + tid * 2],     s10);
  atomicAdd(&mf[512 + tid * 2 + 1], s11);
}

// ---------------------------------------------------------------------------
// gemm_agg: agg column sums = sum_rows w(row) * tanh(patches[row] @ W_a1),
// single-product bf16, rows indirected through compacted list.
// ---------------------------------------------------------------------------
__global__ __launch_bounds__(256, 4)
void gemm_agg(const unsigned short* __restrict__ Ptch,
              const unsigned short* __restrict__ Bhg,
              float* __restrict__ aggsum,
              const int* __restrict__ cidx,
              const float* __restrict__ wgt,
              const int* __restrict__ params)
{
  __shared__ __align__(16) unsigned short Ah[4096];
  __shared__ __align__(16) unsigned short Bh[4096];
  __shared__ int   cidxl[128];
  __shared__ float wl[128];

  const int tid = threadIdx.x;
  const int L = blockIdx.y * 4 + blockIdx.x;
  const int g = L & 7, s = L >> 3;
  const int m0 = ((g << 6) | (s >> 2)) * 128;
  const int n0 = (s & 3) * 128;
  const int count = params[21];
  if (m0 >= count) return;
  if (tid < 128){
    int gi = m0 + tid;
    if (gi < count){ cidxl[tid] = cidx[gi]; wl[tid] = wgt[gi]; }
    else           { cidxl[tid] = 0;        wl[tid] = 0.f;    }
  }
  __syncthreads();

  const int lane = tid & 63;
  const int wv   = tid >> 6;
  const int wm   = (wv & 1) << 6;
  const int wn   = (wv >> 1) << 6;
  const int lr   = lane & 15;
  const int quad = lane >> 4;

  const int ar = tid >> 2;       // 0..63
  const int aq = tid & 3;

  floatx4 acc[4][4];
  #pragma unroll
  for (int i = 0; i < 4; i++)
    #pragma unroll
    for (int j = 0; j < 4; j++)
      acc[i][j] = (floatx4){0.f, 0.f, 0.f, 0.f};

  for (int kb = 0; kb < 16; ++kb){
    const int k0 = kb << 5;
    #pragma unroll
    for (int it = 0; it < 2; it++){
      const int row = ar + it * 64;
      ushortx8 v = *(const ushortx8*)(Ptch + (size_t)cidxl[row] * PDIM + k0 + aq * 8);
      *(ushortx8*)&Ah[lds_off(row, aq)] = v;
      ushortx8 bv = *(const ushortx8*)(Bhg + (size_t)(n0 + row) * PDIM + k0 + aq * 8);
      *(ushortx8*)&Bh[lds_off(row, aq)] = bv;
    }
    __syncthreads();
    shortx8 a0[4], b0[4];
    #pragma unroll
    for (int i = 0; i < 4; i++){
      a0[i] = *(const shortx8*)&Ah[lds_off(wm + i * 16 + lr, quad)];
      b0[i] = *(const shortx8*)&Bh[lds_off(wn + i * 16 + lr, quad)];
    }
    #pragma unroll
    for (int i = 0; i < 4; i++)
      #pragma unroll
      for (int j = 0; j < 4; j++)
        acc[i][j] = __builtin_amdgcn_mfma_f32_16x16x32_bf16(a0[i], b0[j], acc[i][j], 0, 0, 0);
    __syncthreads();
  }

  float csum[4] = {0.f, 0.f, 0.f, 0.f};
  #pragma unroll
  for (int i = 0; i < 4; i++){
    const float4 wv4 = *(const float4*)&wl[wm + i * 16 + (quad << 2)];
    #pragma unroll
    for (int j = 0; j < 4; j++){
      csum[j] += ftanh(acc[i][j][0]) * wv4.x + ftanh(acc[i][j][1]) * wv4.y
               + ftanh(acc[i][j][2]) * wv4.z + ftanh(acc[i][j][3]) * wv4.w;
    }
  }
  #pragma unroll
  for (int j = 0; j < 4; j++){
    float sJ = csum[j];
    sJ += __shfl_xor(sJ, 16);
    sJ += __shfl_xor(sJ, 32);
    if (lane < 16) atomicAdd(&aggsum[n0 + wn + j * 16 + lane], sJ);
  }
}

// ---------------------------------------------------------------------------
// finalize: all small outputs.
// d_out: [0,2) e_Y_logits | [2] e_Y_hat | [3,5) Y_logits | [5,7) Y_prob |
//        [7] Y_hat | [8,131080) router_logits | [131080] joint | [131081,85) distribute
// ---------------------------------------------------------------------------
__global__ void finalize(const float* __restrict__ bagsum, const float* __restrict__ aggsum,
                         const float* __restrict__ mf, const int* __restrict__ params,
                         const float* __restrict__ Wcls1, const float* __restrict__ Wclf,
                         const float* __restrict__ Wacls, float* __restrict__ dout)
{
  const int lane = threadIdx.x;  // 64 threads
  const int nums0 = params[3], nums1 = params[4], nums2 = params[5];
  const float invT = 1.0f / 65536.0f;
  const float inv0 = 1.0f / (float)(nums0 > 0 ? nums0 : 1);
  const float inv1 = 1.0f / (float)(nums1 > 0 ? nums1 : 1);
  const float totn = (float)(nums0 + nums1 + nums2);
  const float invA = 1.0f / fmaxf(totn, 1.0f);
  float y0 = 0, y1 = 0, a0 = 0, a1 = 0;
  float l00 = 0, l01 = 0, l02 = 0, l10 = 0, l11 = 0, l12 = 0;
  #pragma unroll
  for (int j = 0; j < 8; j++){
    int p = lane * 8 + j;
    float bg = bagsum[p] * invT;
    y0 += bg * Wcls1[p * 2]; y1 += bg * Wcls1[p * 2 + 1];
    float ag = aggsum[p] * invA;
    a0 += ag * Wacls[p * 2]; a1 += ag * Wacls[p * 2 + 1];
    float m0v = mf[p] * inv0;
    l00 += m0v * Wclf[p * 3]; l01 += m0v * Wclf[p * 3 + 1]; l02 += m0v * Wclf[p * 3 + 2];
    float m1v = mf[512 + p] * inv1;
    l10 += m1v * Wclf[1536 + p * 3]; l11 += m1v * Wclf[1536 + p * 3 + 1]; l12 += m1v * Wclf[1536 + p * 3 + 2];
  }
  #pragma unroll
  for (int off = 1; off < 64; off <<= 1){
    y0 += __shfl_xor(y0, off);   y1 += __shfl_xor(y1, off);
    a0 += __shfl_xor(a0, off);   a1 += __shfl_xor(a1, off);
    l00 += __shfl_xor(l00, off); l01 += __shfl_xor(l01, off); l02 += __shfl_xor(l02, off);
    l10 += __shfl_xor(l10, off); l11 += __shfl_xor(l11, off); l12 += __shfl_xor(l12, off);
  }
  if (lane == 0){
    dout[0] = a0; dout[1] = a1;
    dout[2] = (a1 > a0) ? 1.0f : 0.0f;
    dout[3] = y0; dout[4] = y1;
    float mx = fmaxf(y0, y1), e0 = expf(y0 - mx), e1 = expf(y1 - mx), inv = 1.0f / (e0 + e1);
    dout[5] = e0 * inv; dout[6] = e1 * inv;
    dout[7] = (y1 > y0) ? 1.0f : 0.0f;
    float m3 = fmaxf(fmaxf(l00, l01), l02);
    float lse0 = m3 + logf(expf(l00 - m3) + expf(l01 - m3) + expf(l02 - m3));
    float m4 = fmaxf(fmaxf(l10, l11), l12);
    float lse1 = m4 + logf(expf(l10 - m4) + expf(l11 - m4) + expf(l12 - m4));
    dout[131080] = (lse0 - l00) + (lse1 - l11);
    dout[131081] = 65536.0f;
    dout[131082] = (float)nums0;
    dout[131083] = (float)nums1;
    dout[131084] = (float)nums2;
  }
}

// ---------------------------------------------------------------------------
extern "C" void kernel_launch(void* const* d_in, const int* in_sizes, int n_in,
                              void* d_out, int out_size, void* d_ws, size_t ws_size,
                              hipStream_t stream)
{
  const float* X      = (const float*)d_in[0];
  const float* W_t1   = (const float*)d_in[1];
  const float* W_cls1 = (const float*)d_in[2];
  const float* Wg0    = (const float*)d_in[3];
  const float* Wg1    = (const float*)d_in[4];
  const float* Wg2    = (const float*)d_in[5];
  const float* W_clf  = (const float*)d_in[6];
  const float* W_a1   = (const float*)d_in[7];
  const float* W_acls = (const float*)d_in[8];
  float* dout = (float*)d_out;
  char* ws = (char*)d_ws;

  // workspace layout (bytes)
  unsigned short* Ptch  = (unsigned short*)(ws + 0);           // 67108864
  unsigned short* W1th  = (unsigned short*)(ws + 67108864);    // 1048576
  unsigned short* W1tl  = (unsigned short*)(ws + 68157440);    // 1048576
  unsigned short* Wath  = (unsigned short*)(ws + 69206016);    // 524288
  unsigned int*   wkey  = (unsigned int*)  (ws + 69730304);    // 262144
  unsigned char*  mask3 = (unsigned char*) (ws + 69992448);    // 65536
  unsigned char*  selb  = (unsigned char*) (ws + 70057984);    // 196608
  int*            cidx  = (int*)           (ws + 70254592);    // 262144
  float*          wgt   = (float*)         (ws + 70516736);    // 262144
  int*            zbase = (int*)           (ws + 70778880);    // 413760*4 zeroed
  float* glog   = (float*)zbase;                               // 65536*6
  int*   hist   = zbase + 393216;                              // 3*4096
  int*   h2     = zbase + 405504;                              // 3*2048
  int*   params = zbase + 411648;                              // 64
  float* bagsum = (float*)(zbase + 411712);                    // 512
  float* aggsum = (float*)(zbase + 412224);                    // 512
  float* mf     = (float*)(zbase + 412736);                    // 1024 (end 413760)

  prep<<<597, 256, 0, stream>>>(W_t1, W_a1, W1th, W1tl, Wath, zbase);

  gemm_main<<<dim3(4, 512), 256, 0, stream>>>(
      X, W1th, W1tl, Ptch, bagsum, glog, Wg0, Wg1, Wg2);

  gates_small<<<256, 256, 0, stream>>>(glog, dout, wkey, mask3, params, hist);

  find_bucket<<<1, 256, 0, stream>>>(params, hist);
  level2hist<<<dim3(32, 3), 256, 0, stream>>>(params, wkey, mask3, h2);
  find_theta<<<3, 256, 0, stream>>>(params, h2);
  mark_sel<<<dim3(32, 3), 256, 0, stream>>>(params, wkey, mask3, selb);
  compact<<<256, 256, 0, stream>>>(selb, cidx, wgt, params);

  meanfeat_c<<<256, 256, 0, stream>>>(Ptch, selb, cidx, params, mf);

  gemm_agg<<<dim3(4, 512), 256, 0, stream>>>(Ptch, Wath, aggsum, cidx, wgt, params);

  finalize<<<1, 64, 0, stream>>>(bagsum, aggsum, mf, params, W_cls1, W_clf, W_acls, dout);
}

// Round 5
// 924.730 us; speedup vs baseline: 1.1121x; 1.1121x over previous
//
#include <hip/hip_runtime.h>
#include <cstdint>
#include <cstddef>

// Problem constants (B=1, S=65536, D=1024, P=512, E=3, C=2)
#define T_TOK 65536
#define DDIM  1024
#define PDIM  512

typedef __attribute__((ext_vector_type(8))) short          shortx8;
typedef __attribute__((ext_vector_type(8))) unsigned short ushortx8;
typedef __attribute__((ext_vector_type(4))) float          floatx4;

__device__ __forceinline__ unsigned short f2bf_rn(float x){
  unsigned int u = __float_as_uint(x);
  unsigned int r = u + 0x7FFFu + ((u >> 16) & 1u);
  return (unsigned short)(r >> 16);
}
__device__ __forceinline__ float bf2f(unsigned short h){
  return __uint_as_float(((unsigned int)h) << 16);
}
// fast tanh, NaN-safe
__device__ __forceinline__ float ftanh(float x){
  float ez = __expf(2.f * x);
  return 1.f - 2.f / (ez + 1.f);
}
// Swizzled LDS K-tile [128 rows][32 k] bf16, row stride 64 B.
// 16B block q (0..3) stored at q ^ ((row>>1)&3): b128 frag reads conflict-free.
__device__ __forceinline__ int lds_off(int row, int q){
  return row * 32 + ((q ^ ((row >> 1) & 3)) << 3);
}
// Swizzled C-staging tile [128 rows][128 cols] bf16 (32 KB), 16B-block xor.
__device__ __forceinline__ int cst(int row, int col){
  return row * 128 + ((((col >> 3) ^ (row & 15))) << 3) + (col & 7);
}
// XCD-balanced block remap: L -> (m_idx, n). XCD presumed = L%8; the 4
// same-m n-blocks sit 8 apart (same XCD) for L2 m-slab reuse; m_idx = q*8+g
// spreads any live-prefix of m across all 8 XCDs (gemm_agg early-exits).
__device__ __forceinline__ void remap(int L, int& m_idx, int& n){
  int g = L & 7, s = L >> 3;
  m_idx = (s >> 2) * 8 + g;
  n = s & 3;
}

// ---------------------------------------------------------------------------
// prep: blocks 0..127: tiled transpose W_t1 (1024x512) -> split hi/lo bf16
//       [p][k]; blocks 128..191: transpose W_a1 (512x512) -> bf16 [n][k];
//       blocks 192+: zero the accumulator/histogram region (int4 stores).
// ---------------------------------------------------------------------------
__global__ void prep(const float* __restrict__ Wt1, const float* __restrict__ Wa1,
                     unsigned short* __restrict__ W1th, unsigned short* __restrict__ W1tl,
                     unsigned short* __restrict__ Wath, int* __restrict__ zbase)
{
  __shared__ float tile[64][65];
  const int b = blockIdx.x, tid = threadIdx.x;
  if (b < 128){
    const int k0 = (b >> 3) * 64, p0 = (b & 7) * 64;
    #pragma unroll
    for (int it = 0; it < 4; it++){
      int lin = it * 256 + tid;
      int r = lin >> 4, c = (lin & 15) << 2;
      float4 v = *(const float4*)(Wt1 + (size_t)(k0 + r) * PDIM + p0 + c);
      tile[r][c] = v.x; tile[r][c + 1] = v.y; tile[r][c + 2] = v.z; tile[r][c + 3] = v.w;
    }
    __syncthreads();
    #pragma unroll
    for (int it = 0; it < 4; it++){
      int lin = it * 256 + tid;
      int pr = lin >> 4, kc = (lin & 15) << 2;
      ushort4 h, l;
      float x0 = tile[kc][pr], x1 = tile[kc + 1][pr], x2 = tile[kc + 2][pr], x3 = tile[kc + 3][pr];
      h.x = f2bf_rn(x0); l.x = f2bf_rn(x0 - bf2f(h.x));
      h.y = f2bf_rn(x1); l.y = f2bf_rn(x1 - bf2f(h.y));
      h.z = f2bf_rn(x2); l.z = f2bf_rn(x2 - bf2f(h.z));
      h.w = f2bf_rn(x3); l.w = f2bf_rn(x3 - bf2f(h.w));
      size_t o = (size_t)(p0 + pr) * DDIM + k0 + kc;
      *(ushort4*)(W1th + o) = h;
      *(ushort4*)(W1tl + o) = l;
    }
  } else if (b < 192){
    const int bb = b - 128;
    const int k0 = (bb >> 3) * 64, n0 = (bb & 7) * 64;
    #pragma unroll
    for (int it = 0; it < 4; it++){
      int lin = it * 256 + tid;
      int r = lin >> 4, c = (lin & 15) << 2;
      float4 v = *(const float4*)(Wa1 + (size_t)(k0 + r) * PDIM + n0 + c);
      tile[r][c] = v.x; tile[r][c + 1] = v.y; tile[r][c + 2] = v.z; tile[r][c + 3] = v.w;
    }
    __syncthreads();
    #pragma unroll
    for (int it = 0; it < 4; it++){
      int lin = it * 256 + tid;
      int nr = lin >> 4, kc = (lin & 15) << 2;
      ushort4 h;
      h.x = f2bf_rn(tile[kc][nr]);
      h.y = f2bf_rn(tile[kc + 1][nr]);
      h.z = f2bf_rn(tile[kc + 2][nr]);
      h.w = f2bf_rn(tile[kc + 3][nr]);
      *(ushort4*)(Wath + (size_t)(n0 + nr) * PDIM + k0 + kc) = h;
    }
  } else {
    int idx = (b - 192) * 256 + tid;
    if (idx < 103440){
      int4 z; z.x = 0; z.y = 0; z.z = 0; z.w = 0;
      ((int4*)zbase)[idx] = z;
    }
  }
}

// ---------------------------------------------------------------------------
// gemm_main: patches = tanh(X @ W_t1), split-bf16 3-product (~fp32 accurate).
// 128x128 tile, BK=32, 256 threads. XCD-balanced remap. Epilogue: LDS
// C-staging -> coalesced cached bf16 stores (full lines), bag column sums,
// fused gate GEMV partials -> atomicAdd glog[t][6].
// ---------------------------------------------------------------------------
__global__ __launch_bounds__(256, 4)
void gemm_main(const float* __restrict__ A,
               const unsigned short* __restrict__ Bhg,
               const unsigned short* __restrict__ Blg,
               unsigned short* __restrict__ Ptch,
               float* __restrict__ bagsum,
               float* __restrict__ glog,
               const float* __restrict__ Wg0,
               const float* __restrict__ Wg1,
               const float* __restrict__ Wg2)
{
  __shared__ __align__(16) unsigned short smem[16384];   // 32 KB
  unsigned short* Ah = smem;
  unsigned short* Al = smem + 4096;
  unsigned short* Bh = smem + 8192;
  unsigned short* Bl = smem + 12288;

  const int tid = threadIdx.x;
  int m_idx, nb;
  remap(blockIdx.y * 4 + blockIdx.x, m_idx, nb);
  const int m0 = m_idx * 128;
  const int n0 = nb * 128;

  const int lane = tid & 63;
  const int wv   = tid >> 6;
  const int wm   = (wv & 1) << 6;
  const int wn   = (wv >> 1) << 6;
  const int lr   = lane & 15;
  const int quad = lane >> 4;

  // A staging addressing (coalesced 16B/lane)
  const int ar  = tid >> 3;               // 0..31
  const int akq = (tid & 7) << 2;         // element 0,4,..28
  const int aq  = akq >> 3;               // 16B block
  const int ak4 = akq & 7;                // 0 or 4
  const float* asrc = A + (size_t)(m0 + ar) * DDIM + akq;
  // B staging addressing
  const int br = tid >> 2;                // 0..63
  const int bq = tid & 3;
  const size_t boff0 = (size_t)(n0 + br) * DDIM + bq * 8;

  floatx4 acc[4][4];
  #pragma unroll
  for (int i = 0; i < 4; i++)
    #pragma unroll
    for (int j = 0; j < 4; j++)
      acc[i][j] = (floatx4){0.f, 0.f, 0.f, 0.f};

  for (int kb = 0; kb < 32; ++kb){
    const int k0 = kb << 5;
    // stage A: fp32 -> hi/lo bf16 (truncation split), coalesced float4 loads
    #pragma unroll
    for (int i = 0; i < 4; i++){
      const int row = ar + i * 32;
      float4 v = *(const float4*)(asrc + (size_t)i * 32 * DDIM + k0);
      unsigned int ux = __float_as_uint(v.x), uy = __float_as_uint(v.y);
      unsigned int uz = __float_as_uint(v.z), uw = __float_as_uint(v.w);
      float rx = v.x - __uint_as_float(ux & 0xFFFF0000u);
      float ry = v.y - __uint_as_float(uy & 0xFFFF0000u);
      float rz = v.z - __uint_as_float(uz & 0xFFFF0000u);
      float rw = v.w - __uint_as_float(uw & 0xFFFF0000u);
      ushort4 h, l;
      h.x = (unsigned short)(ux >> 16); l.x = (unsigned short)(__float_as_uint(rx) >> 16);
      h.y = (unsigned short)(uy >> 16); l.y = (unsigned short)(__float_as_uint(ry) >> 16);
      h.z = (unsigned short)(uz >> 16); l.z = (unsigned short)(__float_as_uint(rz) >> 16);
      h.w = (unsigned short)(uw >> 16); l.w = (unsigned short)(__float_as_uint(rw) >> 16);
      const int off = row * 32 + ((aq ^ ((row >> 1) & 3)) << 3) + ak4;
      *(ushort4*)&Ah[off] = h;
      *(ushort4*)&Al[off] = l;
    }
    // stage B (pre-split bf16 [n][k]), 16B/lane
    #pragma unroll
    for (int it = 0; it < 2; it++){
      const int row = br + it * 64;
      const size_t off = boff0 + (size_t)it * 64 * DDIM + k0;
      const int d = lds_off(row, bq);
      *(ushortx8*)&Bh[d] = *(const ushortx8*)(Bhg + off);
      *(ushortx8*)&Bl[d] = *(const ushortx8*)(Blg + off);
    }
    __syncthreads();
    shortx8 a0[4], a1[4], b0[4], b1[4];
    #pragma unroll
    for (int i = 0; i < 4; i++){
      a0[i] = *(const shortx8*)&Ah[lds_off(wm + i * 16 + lr, quad)];
      a1[i] = *(const shortx8*)&Al[lds_off(wm + i * 16 + lr, quad)];
      b0[i] = *(const shortx8*)&Bh[lds_off(wn + i * 16 + lr, quad)];
      b1[i] = *(const shortx8*)&Bl[lds_off(wn + i * 16 + lr, quad)];
    }
    #pragma unroll
    for (int i = 0; i < 4; i++){
      #pragma unroll
      for (int j = 0; j < 4; j++){
        acc[i][j] = __builtin_amdgcn_mfma_f32_16x16x32_bf16(a0[i], b0[j], acc[i][j], 0, 0, 0);
        acc[i][j] = __builtin_amdgcn_mfma_f32_16x16x32_bf16(a1[i], b0[j], acc[i][j], 0, 0, 0);
        acc[i][j] = __builtin_amdgcn_mfma_f32_16x16x32_bf16(a0[i], b1[j], acc[i][j], 0, 0, 0);
      }
    }
    __syncthreads();
  }

  // gate weights for this lane's 4 columns
  float wgr[4][6];
  #pragma unroll
  for (int j = 0; j < 4; j++){
    int c = n0 + wn + j * 16 + lr;
    wgr[j][0] = Wg0[c * 2]; wgr[j][1] = Wg0[c * 2 + 1];
    wgr[j][2] = Wg1[c * 2]; wgr[j][3] = Wg1[c * 2 + 1];
    wgr[j][4] = Wg2[c * 2]; wgr[j][5] = Wg2[c * 2 + 1];
  }

  // epilogue: tanh -> LDS C-tile (bf16) + bag sums + gate partials
  float csum[4] = {0.f, 0.f, 0.f, 0.f};
  #pragma unroll
  for (int i = 0; i < 4; i++){
    float gp[4][6];
    #pragma unroll
    for (int k = 0; k < 4; k++)
      #pragma unroll
      for (int gg = 0; gg < 6; gg++) gp[k][gg] = 0.f;
    const int r0 = wm + i * 16 + quad * 4;
    #pragma unroll
    for (int j = 0; j < 4; j++){
      float t0 = ftanh(acc[i][j][0]);
      float t1 = ftanh(acc[i][j][1]);
      float t2 = ftanh(acc[i][j][2]);
      float t3 = ftanh(acc[i][j][3]);
      const int col = wn + j * 16 + lr;
      smem[cst(r0 + 0, col)] = f2bf_rn(t0);
      smem[cst(r0 + 1, col)] = f2bf_rn(t1);
      smem[cst(r0 + 2, col)] = f2bf_rn(t2);
      smem[cst(r0 + 3, col)] = f2bf_rn(t3);
      csum[j] += t0 + t1 + t2 + t3;
      #pragma unroll
      for (int gg = 0; gg < 6; gg++){
        gp[0][gg] += t0 * wgr[j][gg];
        gp[1][gg] += t1 * wgr[j][gg];
        gp[2][gg] += t2 * wgr[j][gg];
        gp[3][gg] += t3 * wgr[j][gg];
      }
    }
    #pragma unroll
    for (int st = 1; st < 16; st <<= 1){
      #pragma unroll
      for (int k = 0; k < 4; k++)
        #pragma unroll
        for (int gg = 0; gg < 6; gg++)
          gp[k][gg] += __shfl_xor(gp[k][gg], st);
    }
    if (lr == 0){
      #pragma unroll
      for (int k = 0; k < 4; k++)
        #pragma unroll
        for (int gg = 0; gg < 6; gg++)
          atomicAdd(&glog[(size_t)(m0 + r0 + k) * 6 + gg], gp[k][gg]);
    }
  }
  __syncthreads();
  // coalesced cached patch store: each 16 lanes write 256 B contiguous
  // (2 full 128 B lines per instruction); L2 merges, writes back 64 MB total.
  {
    const int rr = tid >> 4;            // 0..15
    const int cb = tid & 15;            // 16B block within the 128-col row
    #pragma unroll
    for (int it = 0; it < 8; it++){
      const int row = rr + it * 16;
      const int blk = cb ^ (row & 15);
      floatx4 v = *(floatx4*)&smem[row * 128 + (blk << 3)];
      *(floatx4*)(Ptch + (size_t)(m0 + row) * PDIM + n0 + cb * 8) = v;
    }
  }
  // bag column sums
  #pragma unroll
  for (int j = 0; j < 4; j++){
    float sJ = csum[j];
    sJ += __shfl_xor(sJ, 16);
    sJ += __shfl_xor(sJ, 32);
    if (lane < 16) atomicAdd(&bagsum[n0 + wn + j * 16 + lane], sJ);
  }
}

// ---------------------------------------------------------------------------
// gates_small: from glog[t][6] compute router_logits out, masks, keys,
// counts, 4096-bin level-1 histograms.
// ---------------------------------------------------------------------------
__global__ void gates_small(const float* __restrict__ glog, float* __restrict__ dout,
                            unsigned int* __restrict__ wkey, unsigned char* __restrict__ mask3,
                            int* __restrict__ params, int* __restrict__ hist)
{
  __shared__ int lc[3];
  const int tid = threadIdx.x;
  if (tid < 3) lc[tid] = 0;
  __syncthreads();
  const int t = blockIdx.x * 256 + tid;
  float2 p0 = *(const float2*)(glog + (size_t)t * 6);
  float2 p1 = *(const float2*)(glog + (size_t)t * 6 + 2);
  float2 p2 = *(const float2*)(glog + (size_t)t * 6 + 4);
  dout[8 + 2 * t]     = p0.x;
  dout[8 + 2 * t + 1] = p0.y;
  int m0 = p0.y > p0.x;
  int m1 = p1.y > p1.x;
  int m2 = p2.y > p2.x;
  mask3[t] = (unsigned char)(m0 | (m1 << 1) | (m2 << 2));
  float d = fabsf(p0.x - p0.y);
  float w = 1.0f / (1.0f + __expf(-d));
  unsigned int u = __float_as_uint(w);
  u = u < 0x3F000000u ? 0x3F000000u : u;
  u = u > 0x3F7FFFFFu ? 0x3F7FFFFFu : u;
  wkey[t] = u;
  int b = (int)((u >> 11) & 0xFFFu);
  if (m0){ atomicAdd(&hist[b], 1);        atomicAdd(&lc[0], 1); }
  if (m1){ atomicAdd(&hist[4096 + b], 1); atomicAdd(&lc[1], 1); }
  if (m2){ atomicAdd(&hist[8192 + b], 1); atomicAdd(&lc[2], 1); }
  __syncthreads();
  if (tid < 3 && lc[tid]) atomicAdd(&params[tid], lc[tid]);
}

// ---------------------------------------------------------------------------
// find_bucket: nums via shifts; 12-bit bucket of nums-th largest (suffix scan)
// params: [0..2] cnt [3..5] nums [6..8] bucket [9..11] rank-in-bucket
//         [12..14] theta_u [15..17] r_ties [18..20] c_eq [21] compact count
// ---------------------------------------------------------------------------
__global__ void find_bucket(int* __restrict__ params, const int* __restrict__ hist)
{
  __shared__ int cs[256], orig[256];
  __shared__ int selc, selrk;
  const int tid = threadIdx.x;
  for (int e = 0; e < 3; e++){
    int cnt = params[e];
    int shift = (e == 1) ? 1 : 2;
    int nums = cnt >> shift;
    if (nums == 0) nums = cnt;
    if (tid == 0) params[3 + e] = nums;
    __syncthreads();
    if (nums == 0){
      if (tid == 0){ params[6 + e] = -1; params[9 + e] = 0; }
      __syncthreads();
      continue;
    }
    const int* h = hist + e * 4096 + tid * 16;
    int s = 0;
    #pragma unroll
    for (int j = 0; j < 16; j++) s += h[j];
    cs[tid] = s; orig[tid] = s;
    __syncthreads();
    for (int off = 1; off < 256; off <<= 1){
      int v = (tid + off < 256) ? cs[tid + off] : 0;
      __syncthreads();
      cs[tid] += v;
      __syncthreads();
    }
    if (cs[tid] >= nums && (cs[tid] - orig[tid]) < nums){
      selc = tid; selrk = nums - (cs[tid] - orig[tid]);
    }
    __syncthreads();
    if (tid == 0){
      int ch = selc, rk = selrk;
      const int* hh = hist + e * 4096 + ch * 16;
      int acc = 0;
      for (int j = 15; j >= 0; j--){
        int c = hh[j];
        if (acc + c >= rk){ params[6 + e] = ch * 16 + j; params[9 + e] = rk - acc; break; }
        acc += c;
      }
    }
    __syncthreads();
  }
}

// ---------------------------------------------------------------------------
// level2hist: 2048-bin histogram (mantissa bits [10:0]) within chosen bucket.
// ---------------------------------------------------------------------------
__global__ void level2hist(const int* __restrict__ params, const unsigned int* __restrict__ wkey,
                           const unsigned char* __restrict__ mask3, int* __restrict__ h2)
{
  const int e = blockIdx.y;
  const int B = params[6 + e];
  if (B < 0) return;
  const unsigned char bit = (unsigned char)(1u << e);
  const int t0 = blockIdx.x * 2048 + threadIdx.x;
  #pragma unroll
  for (int i = 0; i < 8; i++){
    int t = t0 + i * 256;
    if (mask3[t] & bit){
      unsigned int u = wkey[t];
      if ((int)((u >> 11) & 0xFFFu) == B) atomicAdd(&h2[e * 2048 + (u & 2047u)], 1);
    }
  }
}

// ---------------------------------------------------------------------------
// find_theta: exact 23-bit threshold key, ties-to-take r, tie count c_eq.
// ---------------------------------------------------------------------------
__global__ void find_theta(int* __restrict__ params, const int* __restrict__ h2)
{
  const int e = blockIdx.x;
  const int tid = threadIdx.x;
  __shared__ int cs[256], orig[256];
  __shared__ int selc;
  int B = params[6 + e], rank = params[9 + e];
  if (B < 0){
    if (tid == 0){ params[12 + e] = (int)0xFFFFFFFFu; params[15 + e] = 0; params[18 + e] = 0; }
    return;
  }
  const int* h = h2 + e * 2048 + tid * 8;
  int s = 0;
  #pragma unroll
  for (int j = 0; j < 8; j++) s += h[j];
  cs[tid] = s; orig[tid] = s;
  __syncthreads();
  for (int off = 1; off < 256; off <<= 1){
    int v = (tid + off < 256) ? cs[tid + off] : 0;
    __syncthreads();
    cs[tid] += v;
    __syncthreads();
  }
  if (cs[tid] >= rank && (cs[tid] - orig[tid]) < rank) selc = tid;
  __syncthreads();
  if (tid == 0){
    int ch = selc;
    int rk = rank - (cs[ch] - orig[ch]);
    const int* hh = h2 + e * 2048 + ch * 8;
    int acc = 0;
    for (int j = 7; j >= 0; j--){
      int c = hh[j];
      if (acc + c >= rk){
        int sub = ch * 8 + j;
        params[12 + e] = (int)(0x3F000000u | ((unsigned)B << 11) | (unsigned)sub);
        params[15 + e] = rk - acc;
        params[18 + e] = c;
        break;
      }
      acc += c;
    }
  }
}

// ---------------------------------------------------------------------------
// mark_sel: fast parallel path when all ties taken; stable scan otherwise.
// ---------------------------------------------------------------------------
__global__ void mark_sel(const int* __restrict__ params, const unsigned int* __restrict__ wkey,
                         const unsigned char* __restrict__ mask3, unsigned char* __restrict__ selb)
{
  const int e = blockIdx.y;
  const int bx = blockIdx.x;
  const int tid = threadIdx.x;
  const unsigned int theta = (unsigned int)params[12 + e];
  const int r = params[15 + e];
  const int ceq = params[18 + e];
  const unsigned char bit = (unsigned char)(1u << e);
  unsigned char* sb = selb + e * T_TOK;
  if (ceq == r){
    int t0 = bx * 2048;
    #pragma unroll
    for (int i = 0; i < 8; i++){
      int t = t0 + i * 256 + tid;
      unsigned char mk = mask3[t] & bit;
      sb[t] = (mk && wkey[t] >= theta) ? 1 : 0;
    }
  } else {
    if (bx) return;
    __shared__ int basec;
    __shared__ int wsum[4];
    if (tid == 0) basec = 0;
    __syncthreads();
    const int lane = tid & 63, w = tid >> 6;
    for (int c = 0; c < 256; c++){
      int t = c * 256 + tid;
      unsigned char mk = mask3[t] & bit;
      unsigned int u = mk ? wkey[t] : 0u;
      bool gt = mk && (u > theta);
      bool eq = mk && (u == theta);
      unsigned long long bal = __ballot(eq);
      if (lane == 0) wsum[w] = __popcll(bal);
      __syncthreads();
      int wbase = 0;
      for (int ww = 0; ww < w; ww++) wbase += wsum[ww];
      int pos = basec + wbase + __popcll(bal & ((1ull << lane) - 1ull));
      sb[t] = (gt || (eq && pos < r)) ? 1 : 0;
      __syncthreads();
      if (tid == 0) basec += wsum[0] + wsum[1] + wsum[2] + wsum[3];
      __syncthreads();
    }
  }
}

// ---------------------------------------------------------------------------
// compact: tokens with total_sel>0 + multiplicity weight; count in params[21].
// ---------------------------------------------------------------------------
__global__ void compact(const unsigned char* __restrict__ selb, int* __restrict__ cidx,
                        float* __restrict__ wgt, int* __restrict__ params)
{
  int t = blockIdx.x * 256 + threadIdx.x;
  int ts = selb[t] + selb[T_TOK + t] + selb[2 * T_TOK + t];
  int lane = threadIdx.x & 63;
  unsigned long long bal = __ballot(ts > 0);
  int base = 0;
  if (lane == 0) base = atomicAdd(&params[21], __popcll(bal));
  base = __shfl(base, 0);
  if (ts){
    int pos = base + __popcll(bal & ((1ull << lane) - 1ull));
    cidx[pos] = t;
    wgt[pos] = (float)ts;
  }
}

// ---------------------------------------------------------------------------
// meanfeat_c: column sums of (bf16) patches over sel0/sel1 rows, via the
// compacted union list.
// ---------------------------------------------------------------------------
__global__ void meanfeat_c(const unsigned short* __restrict__ Ptch,
                           const unsigned char* __restrict__ selb,
                           const int* __restrict__ cidx, const int* __restrict__ params,
                           float* __restrict__ mf)
{
  const int count = params[21];
  const int base = blockIdx.x * 256;
  if (base >= count) return;
  const int n = min(256, count - base);
  const int tid = threadIdx.x;
  __shared__ int cl[256];
  __shared__ unsigned char f0s[256], f1s[256];
  if (tid < n){
    int c = cidx[base + tid];
    cl[tid] = c;
    f0s[tid] = selb[c];
    f1s[tid] = selb[T_TOK + c];
  }
  __syncthreads();
  float s00 = 0, s01 = 0, s10 = 0, s11 = 0;
  for (int i = 0; i < n; i++){
    int f0 = f0s[i], f1 = f1s[i];
    if (f0 | f1){
      unsigned int u = *(const unsigned int*)(Ptch + (size_t)cl[i] * PDIM + tid * 2);
      float vx = bf2f((unsigned short)(u & 0xFFFFu));
      float vy = bf2f((unsigned short)(u >> 16));
      if (f0){ s00 += vx; s01 += vy; }
      if (f1){ s10 += vx; s11 += vy; }
    }
  }
  atomicAdd(&mf[tid * 2],           s00);
  atomicAdd(&mf[tid * 2 + 1],       s01);
  atomicAdd(&mf[512 + tid * 2],     s10);
  atomicAdd(&mf[512 + tid * 2 + 1], s11);
}

// ---------------------------------------------------------------------------
// gemm_agg: agg column sums = sum_rows w(row) * tanh(patches[row] @ W_a1),
// single-product bf16, rows indirected through compacted list.
// ---------------------------------------------------------------------------
__global__ __launch_bounds__(256, 4)
void gemm_agg(const unsigned short* __restrict__ Ptch,
              const unsigned short* __restrict__ Bhg,
              float* __restrict__ aggsum,
              const int* __restrict__ cidx,
              const float* __restrict__ wgt,
              const int* __restrict__ params)
{
  __shared__ __align__(16) unsigned short Ah[4096];
  __shared__ __align__(16) unsigned short Bh[4096];
  __shared__ int   cidxl[128];
  __shared__ float wl[128];

  const int tid = threadIdx.x;
  int m_idx, nb;
  remap(blockIdx.y * 4 + blockIdx.x, m_idx, nb);
  const int m0 = m_idx * 128;
  const int n0 = nb * 128;
  const int count = params[21];
  if (m0 >= count) return;
  if (tid < 128){
    int gi = m0 + tid;
    if (gi < count){ cidxl[tid] = cidx[gi]; wl[tid] = wgt[gi]; }
    else           { cidxl[tid] = 0;        wl[tid] = 0.f;    }
  }
  __syncthreads();

  const int lane = tid & 63;
  const int wv   = tid >> 6;
  const int wm   = (wv & 1) << 6;
  const int wn   = (wv >> 1) << 6;
  const int lr   = lane & 15;
  const int quad = lane >> 4;

  const int ar = tid >> 2;       // 0..63
  const int aq = tid & 3;

  floatx4 acc[4][4];
  #pragma unroll
  for (int i = 0; i < 4; i++)
    #pragma unroll
    for (int j = 0; j < 4; j++)
      acc[i][j] = (floatx4){0.f, 0.f, 0.f, 0.f};

  for (int kb = 0; kb < 16; ++kb){
    const int k0 = kb << 5;
    #pragma unroll
    for (int it = 0; it < 2; it++){
      const int row = ar + it * 64;
      ushortx8 v = *(const ushortx8*)(Ptch + (size_t)cidxl[row] * PDIM + k0 + aq * 8);
      *(ushortx8*)&Ah[lds_off(row, aq)] = v;
      ushortx8 bv = *(const ushortx8*)(Bhg + (size_t)(n0 + row) * PDIM + k0 + aq * 8);
      *(ushortx8*)&Bh[lds_off(row, aq)] = bv;
    }
    __syncthreads();
    shortx8 a0[4], b0[4];
    #pragma unroll
    for (int i = 0; i < 4; i++){
      a0[i] = *(const shortx8*)&Ah[lds_off(wm + i * 16 + lr, quad)];
      b0[i] = *(const shortx8*)&Bh[lds_off(wn + i * 16 + lr, quad)];
    }
    #pragma unroll
    for (int i = 0; i < 4; i++)
      #pragma unroll
      for (int j = 0; j < 4; j++)
        acc[i][j] = __builtin_amdgcn_mfma_f32_16x16x32_bf16(a0[i], b0[j], acc[i][j], 0, 0, 0);
    __syncthreads();
  }

  float csum[4] = {0.f, 0.f, 0.f, 0.f};
  #pragma unroll
  for (int i = 0; i < 4; i++){
    const float4 wv4 = *(const float4*)&wl[wm + i * 16 + (quad << 2)];
    #pragma unroll
    for (int j = 0; j < 4; j++){
      csum[j] += ftanh(acc[i][j][0]) * wv4.x + ftanh(acc[i][j][1]) * wv4.y
               + ftanh(acc[i][j][2]) * wv4.z + ftanh(acc[i][j][3]) * wv4.w;
    }
  }
  #pragma unroll
  for (int j = 0; j < 4; j++){
    float sJ = csum[j];
    sJ += __shfl_xor(sJ, 16);
    sJ += __shfl_xor(sJ, 32);
    if (lane < 16) atomicAdd(&aggsum[n0 + wn + j * 16 + lane], sJ);
  }
}

// ---------------------------------------------------------------------------
// finalize: all small outputs.
// d_out: [0,2) e_Y_logits | [2] e_Y_hat | [3,5) Y_logits | [5,7) Y_prob |
//        [7] Y_hat | [8,131080) router_logits | [131080] joint | [131081,85) distribute
// ---------------------------------------------------------------------------
__global__ void finalize(const float* __restrict__ bagsum, const float* __restrict__ aggsum,
                         const float* __restrict__ mf, const int* __restrict__ params,
                         const float* __restrict__ Wcls1, const float* __restrict__ Wclf,
                         const float* __restrict__ Wacls, float* __restrict__ dout)
{
  const int lane = threadIdx.x;  // 64 threads
  const int nums0 = params[3], nums1 = params[4], nums2 = params[5];
  const float invT = 1.0f / 65536.0f;
  const float inv0 = 1.0f / (float)(nums0 > 0 ? nums0 : 1);
  const float inv1 = 1.0f / (float)(nums1 > 0 ? nums1 : 1);
  const float totn = (float)(nums0 + nums1 + nums2);
  const float invA = 1.0f / fmaxf(totn, 1.0f);
  float y0 = 0, y1 = 0, a0 = 0, a1 = 0;
  float l00 = 0, l01 = 0, l02 = 0, l10 = 0, l11 = 0, l12 = 0;
  #pragma unroll
  for (int j = 0; j < 8; j++){
    int p = lane * 8 + j;
    float bg = bagsum[p] * invT;
    y0 += bg * Wcls1[p * 2]; y1 += bg * Wcls1[p * 2 + 1];
    float ag = aggsum[p] * invA;
    a0 += ag * Wacls[p * 2]; a1 += ag * Wacls[p * 2 + 1];
    float m0v = mf[p] * inv0;
    l00 += m0v * Wclf[p * 3]; l01 += m0v * Wclf[p * 3 + 1]; l02 += m0v * Wclf[p * 3 + 2];
    float m1v = mf[512 + p] * inv1;
    l10 += m1v * Wclf[1536 + p * 3]; l11 += m1v * Wclf[1536 + p * 3 + 1]; l12 += m1v * Wclf[1536 + p * 3 + 2];
  }
  #pragma unroll
  for (int off = 1; off < 64; off <<= 1){
    y0 += __shfl_xor(y0, off);   y1 += __shfl_xor(y1, off);
    a0 += __shfl_xor(a0, off);   a1 += __shfl_xor(a1, off);
    l00 += __shfl_xor(l00, off); l01 += __shfl_xor(l01, off); l02 += __shfl_xor(l02, off);
    l10 += __shfl_xor(l10, off); l11 += __shfl_xor(l11, off); l12 += __shfl_xor(l12, off);
  }
  if (lane == 0){
    dout[0] = a0; dout[1] = a1;
    dout[2] = (a1 > a0) ? 1.0f : 0.0f;
    dout[3] = y0; dout[4] = y1;
    float mx = fmaxf(y0, y1), e0 = expf(y0 - mx), e1 = expf(y1 - mx), inv = 1.0f / (e0 + e1);
    dout[5] = e0 * inv; dout[6] = e1 * inv;
    dout[7] = (y1 > y0) ? 1.0f : 0.0f;
    float m3 = fmaxf(fmaxf(l00, l01), l02);
    float lse0 = m3 + logf(expf(l00 - m3) + expf(l01 - m3) + expf(l02 - m3));
    float m4 = fmaxf(fmaxf(l10, l11), l12);
    float lse1 = m4 + logf(expf(l10 - m4) + expf(l11 - m4) + expf(l12 - m4));
    dout[131080] = (lse0 - l00) + (lse1 - l11);
    dout[131081] = 65536.0f;
    dout[131082] = (float)nums0;
    dout[131083] = (float)nums1;
    dout[131084] = (float)nums2;
  }
}

// ---------------------------------------------------------------------------
extern "C" void kernel_launch(void* const* d_in, const int* in_sizes, int n_in,
                              void* d_out, int out_size, void* d_ws, size_t ws_size,
                              hipStream_t stream)
{
  const float* X      = (const float*)d_in[0];
  const float* W_t1   = (const float*)d_in[1];
  const float* W_cls1 = (const float*)d_in[2];
  const float* Wg0    = (const float*)d_in[3];
  const float* Wg1    = (const float*)d_in[4];
  const float* Wg2    = (const float*)d_in[5];
  const float* W_clf  = (const float*)d_in[6];
  const float* W_a1   = (const float*)d_in[7];
  const float* W_acls = (const float*)d_in[8];
  float* dout = (float*)d_out;
  char* ws = (char*)d_ws;

  // workspace layout (bytes)
  unsigned short* Ptch  = (unsigned short*)(ws + 0);           // 67108864
  unsigned short* W1th  = (unsigned short*)(ws + 67108864);    // 1048576
  unsigned short* W1tl  = (unsigned short*)(ws + 68157440);    // 1048576
  unsigned short* Wath  = (unsigned short*)(ws + 69206016);    // 524288
  unsigned int*   wkey  = (unsigned int*)  (ws + 69730304);    // 262144
  unsigned char*  mask3 = (unsigned char*) (ws + 69992448);    // 65536
  unsigned char*  selb  = (unsigned char*) (ws + 70057984);    // 196608
  int*            cidx  = (int*)           (ws + 70254592);    // 262144
  float*          wgt   = (float*)         (ws + 70516736);    // 262144
  int*            zbase = (int*)           (ws + 70778880);    // 413760*4 zeroed
  float* glog   = (float*)zbase;                               // 65536*6
  int*   hist   = zbase + 393216;                              // 3*4096
  int*   h2     = zbase + 405504;                              // 3*2048
  int*   params = zbase + 411648;                              // 64
  float* bagsum = (float*)(zbase + 411712);                    // 512
  float* aggsum = (float*)(zbase + 412224);                    // 512
  float* mf     = (float*)(zbase + 412736);                    // 1024 (end 413760)

  prep<<<597, 256, 0, stream>>>(W_t1, W_a1, W1th, W1tl, Wath, zbase);

  gemm_main<<<dim3(4, 512), 256, 0, stream>>>(
      X, W1th, W1tl, Ptch, bagsum, glog, Wg0, Wg1, Wg2);

  gates_small<<<256, 256, 0, stream>>>(glog, dout, wkey, mask3, params, hist);

  find_bucket<<<1, 256, 0, stream>>>(params, hist);
  level2hist<<<dim3(32, 3), 256, 0, stream>>>(params, wkey, mask3, h2);
  find_theta<<<3, 256, 0, stream>>>(params, h2);
  mark_sel<<<dim3(32, 3), 256, 0, stream>>>(params, wkey, mask3, selb);
  compact<<<256, 256, 0, stream>>>(selb, cidx, wgt, params);

  meanfeat_c<<<256, 256, 0, stream>>>(Ptch, selb, cidx, params, mf);

  gemm_agg<<<dim3(4, 512), 256, 0, stream>>>(Ptch, Wath, aggsum, cidx, wgt, params);

  finalize<<<1, 64, 0, stream>>>(bagsum, aggsum, mf, params, W_cls1, W_clf, W_acls, dout);
}

// Round 6
// 738.089 us; speedup vs baseline: 1.3934x; 1.2529x over previous
//
#include <hip/hip_runtime.h>
#include <cstdint>
#include <cstddef>

// Problem constants (B=1, S=65536, D=1024, P=512, E=3, C=2)
#define T_TOK 65536
#define DDIM  1024
#define PDIM  512
#define EQCAP 8192

typedef __attribute__((ext_vector_type(8))) short          shortx8;
typedef __attribute__((ext_vector_type(8))) unsigned short ushortx8;
typedef __attribute__((ext_vector_type(4))) float          floatx4;

__device__ __forceinline__ unsigned short f2bf_rn(float x){
  unsigned int u = __float_as_uint(x);
  unsigned int r = u + 0x7FFFu + ((u >> 16) & 1u);
  return (unsigned short)(r >> 16);
}
__device__ __forceinline__ float bf2f(unsigned short h){
  return __uint_as_float(((unsigned int)h) << 16);
}
// fast tanh, NaN-safe
__device__ __forceinline__ float ftanh(float x){
  float ez = __expf(2.f * x);
  return 1.f - 2.f / (ez + 1.f);
}
// Swizzled LDS K-tile [128 rows][32 k] bf16, row stride 64 B.
__device__ __forceinline__ int lds_off(int row, int q){
  return row * 32 + ((q ^ ((row >> 1) & 3)) << 3);
}
// Swizzled C-staging tile [128 rows][128 cols] bf16 (32 KB), 16B-block xor.
__device__ __forceinline__ int cst(int row, int col){
  return row * 128 + ((((col >> 3) ^ (row & 15))) << 3) + (col & 7);
}
// XCD-balanced block remap (XCD presumed = L%8; 4 same-m n-blocks 8 apart).
__device__ __forceinline__ void remap(int L, int& m_idx, int& n){
  int g = L & 7, s = L >> 3;
  m_idx = (s >> 2) * 8 + g;
  n = s & 3;
}

// ---------------------------------------------------------------------------
// prep: blocks 0..127 transpose+split W_t1; 128..191 transpose W_a1 -> bf16;
// blocks 192+ zero the small accumulator/histogram region.
// ---------------------------------------------------------------------------
__global__ void prep(const float* __restrict__ Wt1, const float* __restrict__ Wa1,
                     unsigned short* __restrict__ W1th, unsigned short* __restrict__ W1tl,
                     unsigned short* __restrict__ Wath, int* __restrict__ zbase)
{
  __shared__ float tile[64][65];
  const int b = blockIdx.x, tid = threadIdx.x;
  if (b < 128){
    const int k0 = (b >> 3) * 64, p0 = (b & 7) * 64;
    #pragma unroll
    for (int it = 0; it < 4; it++){
      int lin = it * 256 + tid;
      int r = lin >> 4, c = (lin & 15) << 2;
      float4 v = *(const float4*)(Wt1 + (size_t)(k0 + r) * PDIM + p0 + c);
      tile[r][c] = v.x; tile[r][c + 1] = v.y; tile[r][c + 2] = v.z; tile[r][c + 3] = v.w;
    }
    __syncthreads();
    #pragma unroll
    for (int it = 0; it < 4; it++){
      int lin = it * 256 + tid;
      int pr = lin >> 4, kc = (lin & 15) << 2;
      ushort4 h, l;
      float x0 = tile[kc][pr], x1 = tile[kc + 1][pr], x2 = tile[kc + 2][pr], x3 = tile[kc + 3][pr];
      h.x = f2bf_rn(x0); l.x = f2bf_rn(x0 - bf2f(h.x));
      h.y = f2bf_rn(x1); l.y = f2bf_rn(x1 - bf2f(h.y));
      h.z = f2bf_rn(x2); l.z = f2bf_rn(x2 - bf2f(h.z));
      h.w = f2bf_rn(x3); l.w = f2bf_rn(x3 - bf2f(h.w));
      size_t o = (size_t)(p0 + pr) * DDIM + k0 + kc;
      *(ushort4*)(W1th + o) = h;
      *(ushort4*)(W1tl + o) = l;
    }
  } else if (b < 192){
    const int bb = b - 128;
    const int k0 = (bb >> 3) * 64, n0 = (bb & 7) * 64;
    #pragma unroll
    for (int it = 0; it < 4; it++){
      int lin = it * 256 + tid;
      int r = lin >> 4, c = (lin & 15) << 2;
      float4 v = *(const float4*)(Wa1 + (size_t)(k0 + r) * PDIM + n0 + c);
      tile[r][c] = v.x; tile[r][c + 1] = v.y; tile[r][c + 2] = v.z; tile[r][c + 3] = v.w;
    }
    __syncthreads();
    #pragma unroll
    for (int it = 0; it < 4; it++){
      int lin = it * 256 + tid;
      int nr = lin >> 4, kc = (lin & 15) << 2;
      ushort4 h;
      h.x = f2bf_rn(tile[kc][nr]);
      h.y = f2bf_rn(tile[kc + 1][nr]);
      h.z = f2bf_rn(tile[kc + 2][nr]);
      h.w = f2bf_rn(tile[kc + 3][nr]);
      *(ushort4*)(Wath + (size_t)(n0 + nr) * PDIM + k0 + kc) = h;
    }
  } else {
    int idx = (b - 192) * 256 + tid;
    if (idx < 5136){
      int4 z; z.x = 0; z.y = 0; z.z = 0; z.w = 0;
      ((int4*)zbase)[idx] = z;
    }
  }
}

// ---------------------------------------------------------------------------
// gemm_main: patches = tanh(X @ W_t1), split-bf16 3-product (~fp32 accurate).
// 128x128 tile, BK=32, 256 threads, XCD-balanced remap. Epilogue: LDS
// C-staging -> coalesced cached bf16 stores; bag column sums (tiny atomics);
// gate GEMV partials via LDS accumulation -> coalesced plain store to
// glog_part[n][t][6]  (NO device-scope atomics in the hot kernel).
// ---------------------------------------------------------------------------
__global__ __launch_bounds__(256, 4)
void gemm_main(const float* __restrict__ A,
               const unsigned short* __restrict__ Bhg,
               const unsigned short* __restrict__ Blg,
               unsigned short* __restrict__ Ptch,
               float* __restrict__ bagsum,
               float* __restrict__ glog_part,
               const float* __restrict__ Wg0,
               const float* __restrict__ Wg1,
               const float* __restrict__ Wg2)
{
  __shared__ __align__(16) unsigned short smem[16384];   // 32 KB
  __shared__ __align__(16) float glds[768];              // 128 rows x 6 gates
  unsigned short* Ah = smem;
  unsigned short* Al = smem + 4096;
  unsigned short* Bh = smem + 8192;
  unsigned short* Bl = smem + 12288;

  const int tid = threadIdx.x;
  int m_idx, nb;
  remap(blockIdx.y * 4 + blockIdx.x, m_idx, nb);
  const int m0 = m_idx * 128;
  const int n0 = nb * 128;

  // zero gate accumulator
  glds[tid * 3] = 0.f; glds[tid * 3 + 1] = 0.f; glds[tid * 3 + 2] = 0.f;

  const int lane = tid & 63;
  const int wv   = tid >> 6;
  const int wm   = (wv & 1) << 6;
  const int wn   = (wv >> 1) << 6;
  const int lr   = lane & 15;
  const int quad = lane >> 4;

  const int ar  = tid >> 3;
  const int akq = (tid & 7) << 2;
  const int aq  = akq >> 3;
  const int ak4 = akq & 7;
  const float* asrc = A + (size_t)(m0 + ar) * DDIM + akq;
  const int br = tid >> 2;
  const int bq = tid & 3;
  const size_t boff0 = (size_t)(n0 + br) * DDIM + bq * 8;

  floatx4 acc[4][4];
  #pragma unroll
  for (int i = 0; i < 4; i++)
    #pragma unroll
    for (int j = 0; j < 4; j++)
      acc[i][j] = (floatx4){0.f, 0.f, 0.f, 0.f};

  for (int kb = 0; kb < 32; ++kb){
    const int k0 = kb << 5;
    #pragma unroll
    for (int i = 0; i < 4; i++){
      const int row = ar + i * 32;
      float4 v = *(const float4*)(asrc + (size_t)i * 32 * DDIM + k0);
      unsigned int ux = __float_as_uint(v.x), uy = __float_as_uint(v.y);
      unsigned int uz = __float_as_uint(v.z), uw = __float_as_uint(v.w);
      float rx = v.x - __uint_as_float(ux & 0xFFFF0000u);
      float ry = v.y - __uint_as_float(uy & 0xFFFF0000u);
      float rz = v.z - __uint_as_float(uz & 0xFFFF0000u);
      float rw = v.w - __uint_as_float(uw & 0xFFFF0000u);
      ushort4 h, l;
      h.x = (unsigned short)(ux >> 16); l.x = (unsigned short)(__float_as_uint(rx) >> 16);
      h.y = (unsigned short)(uy >> 16); l.y = (unsigned short)(__float_as_uint(ry) >> 16);
      h.z = (unsigned short)(uz >> 16); l.z = (unsigned short)(__float_as_uint(rz) >> 16);
      h.w = (unsigned short)(uw >> 16); l.w = (unsigned short)(__float_as_uint(rw) >> 16);
      const int off = row * 32 + ((aq ^ ((row >> 1) & 3)) << 3) + ak4;
      *(ushort4*)&Ah[off] = h;
      *(ushort4*)&Al[off] = l;
    }
    #pragma unroll
    for (int it = 0; it < 2; it++){
      const int row = br + it * 64;
      const size_t off = boff0 + (size_t)it * 64 * DDIM + k0;
      const int d = lds_off(row, bq);
      *(ushortx8*)&Bh[d] = *(const ushortx8*)(Bhg + off);
      *(ushortx8*)&Bl[d] = *(const ushortx8*)(Blg + off);
    }
    __syncthreads();
    shortx8 a0[4], a1[4], b0[4], b1[4];
    #pragma unroll
    for (int i = 0; i < 4; i++){
      a0[i] = *(const shortx8*)&Ah[lds_off(wm + i * 16 + lr, quad)];
      a1[i] = *(const shortx8*)&Al[lds_off(wm + i * 16 + lr, quad)];
      b0[i] = *(const shortx8*)&Bh[lds_off(wn + i * 16 + lr, quad)];
      b1[i] = *(const shortx8*)&Bl[lds_off(wn + i * 16 + lr, quad)];
    }
    #pragma unroll
    for (int i = 0; i < 4; i++){
      #pragma unroll
      for (int j = 0; j < 4; j++){
        acc[i][j] = __builtin_amdgcn_mfma_f32_16x16x32_bf16(a0[i], b0[j], acc[i][j], 0, 0, 0);
        acc[i][j] = __builtin_amdgcn_mfma_f32_16x16x32_bf16(a1[i], b0[j], acc[i][j], 0, 0, 0);
        acc[i][j] = __builtin_amdgcn_mfma_f32_16x16x32_bf16(a0[i], b1[j], acc[i][j], 0, 0, 0);
      }
    }
    __syncthreads();
  }

  // gate weights for this lane's 4 columns
  float wgr[4][6];
  #pragma unroll
  for (int j = 0; j < 4; j++){
    int c = n0 + wn + j * 16 + lr;
    wgr[j][0] = Wg0[c * 2]; wgr[j][1] = Wg0[c * 2 + 1];
    wgr[j][2] = Wg1[c * 2]; wgr[j][3] = Wg1[c * 2 + 1];
    wgr[j][4] = Wg2[c * 2]; wgr[j][5] = Wg2[c * 2 + 1];
  }

  float csum[4] = {0.f, 0.f, 0.f, 0.f};
  #pragma unroll
  for (int i = 0; i < 4; i++){
    float gp[4][6];
    #pragma unroll
    for (int k = 0; k < 4; k++)
      #pragma unroll
      for (int gg = 0; gg < 6; gg++) gp[k][gg] = 0.f;
    const int r0 = wm + i * 16 + quad * 4;
    #pragma unroll
    for (int j = 0; j < 4; j++){
      float t0 = ftanh(acc[i][j][0]);
      float t1 = ftanh(acc[i][j][1]);
      float t2 = ftanh(acc[i][j][2]);
      float t3 = ftanh(acc[i][j][3]);
      const int col = wn + j * 16 + lr;
      smem[cst(r0 + 0, col)] = f2bf_rn(t0);
      smem[cst(r0 + 1, col)] = f2bf_rn(t1);
      smem[cst(r0 + 2, col)] = f2bf_rn(t2);
      smem[cst(r0 + 3, col)] = f2bf_rn(t3);
      csum[j] += t0 + t1 + t2 + t3;
      #pragma unroll
      for (int gg = 0; gg < 6; gg++){
        gp[0][gg] += t0 * wgr[j][gg];
        gp[1][gg] += t1 * wgr[j][gg];
        gp[2][gg] += t2 * wgr[j][gg];
        gp[3][gg] += t3 * wgr[j][gg];
      }
    }
    #pragma unroll
    for (int st = 1; st < 16; st <<= 1){
      #pragma unroll
      for (int k = 0; k < 4; k++)
        #pragma unroll
        for (int gg = 0; gg < 6; gg++)
          gp[k][gg] += __shfl_xor(gp[k][gg], st);
    }
    if (lr == 0){
      // LDS-scope atomic (two waves share each row range) — cheap, no HBM RMW
      #pragma unroll
      for (int k = 0; k < 4; k++)
        #pragma unroll
        for (int gg = 0; gg < 6; gg++)
          atomicAdd(&glds[(r0 + k) * 6 + gg], gp[k][gg]);
    }
  }
  __syncthreads();
  // coalesced cached patch store: 16 lanes -> 256 B contiguous (full lines)
  {
    const int rr = tid >> 4;
    const int cb = tid & 15;
    #pragma unroll
    for (int it = 0; it < 8; it++){
      const int row = rr + it * 16;
      const int blk = cb ^ (row & 15);
      floatx4 v = *(floatx4*)&smem[row * 128 + (blk << 3)];
      *(floatx4*)(Ptch + (size_t)(m0 + row) * PDIM + n0 + cb * 8) = v;
    }
  }
  // gate partial store: 3 KB contiguous per block, plain coalesced
  if (tid < 192){
    floatx4 v = *(floatx4*)&glds[tid * 4];
    *(floatx4*)(glog_part + ((size_t)nb * T_TOK + m0) * 6 + tid * 4) = v;
  }
  // bag column sums (small atomic count, same as fast R2 structure)
  #pragma unroll
  for (int j = 0; j < 4; j++){
    float sJ = csum[j];
    sJ += __shfl_xor(sJ, 16);
    sJ += __shfl_xor(sJ, 32);
    if (lane < 16) atomicAdd(&bagsum[n0 + wn + j * 16 + lane], sJ);
  }
}

// ---------------------------------------------------------------------------
// gates_small: sum 4 glog partials -> router logits, masks, keys, counts,
// 4096-bin level-1 histograms.
// ---------------------------------------------------------------------------
__global__ void gates_small(const float* __restrict__ glog_part, float* __restrict__ dout,
                            unsigned int* __restrict__ wkey, unsigned char* __restrict__ mask3,
                            int* __restrict__ params, int* __restrict__ hist)
{
  __shared__ int lc[3];
  const int tid = threadIdx.x;
  if (tid < 3) lc[tid] = 0;
  __syncthreads();
  const int t = blockIdx.x * 256 + tid;
  float s[6] = {0.f, 0.f, 0.f, 0.f, 0.f, 0.f};
  #pragma unroll
  for (int n = 0; n < 4; n++){
    const float* g = glog_part + ((size_t)n * T_TOK + t) * 6;
    #pragma unroll
    for (int gg = 0; gg < 6; gg++) s[gg] += g[gg];
  }
  dout[8 + 2 * t]     = s[0];
  dout[8 + 2 * t + 1] = s[1];
  int m0 = s[1] > s[0];
  int m1 = s[3] > s[2];
  int m2 = s[5] > s[4];
  mask3[t] = (unsigned char)(m0 | (m1 << 1) | (m2 << 2));
  float d = fabsf(s[0] - s[1]);
  float w = 1.0f / (1.0f + __expf(-d));
  unsigned int u = __float_as_uint(w);
  u = u < 0x3F000000u ? 0x3F000000u : u;
  u = u > 0x3F7FFFFFu ? 0x3F7FFFFFu : u;
  wkey[t] = u;
  int b = (int)((u >> 11) & 0xFFFu);
  if (m0){ atomicAdd(&hist[b], 1);        atomicAdd(&lc[0], 1); }
  if (m1){ atomicAdd(&hist[4096 + b], 1); atomicAdd(&lc[1], 1); }
  if (m2){ atomicAdd(&hist[8192 + b], 1); atomicAdd(&lc[2], 1); }
  __syncthreads();
  if (tid < 3 && lc[tid]) atomicAdd(&params[tid], lc[tid]);
}

// ---------------------------------------------------------------------------
// find_bucket: nums via shifts; 12-bit bucket of nums-th largest (suffix scan)
// params: [0..2] cnt [3..5] nums [6..8] bucket [9..11] rank-in-bucket
//         [12..14] theta_u [15..17] r_ties [18..20] c_eq [21] compact count
//         [22..24] eq-list counts
// ---------------------------------------------------------------------------
__global__ void find_bucket(int* __restrict__ params, const int* __restrict__ hist)
{
  __shared__ int cs[256], orig[256];
  __shared__ int selc, selrk;
  const int tid = threadIdx.x;
  for (int e = 0; e < 3; e++){
    int cnt = params[e];
    int shift = (e == 1) ? 1 : 2;
    int nums = cnt >> shift;
    if (nums == 0) nums = cnt;
    if (tid == 0) params[3 + e] = nums;
    __syncthreads();
    if (nums == 0){
      if (tid == 0){ params[6 + e] = -1; params[9 + e] = 0; }
      __syncthreads();
      continue;
    }
    const int* h = hist + e * 4096 + tid * 16;
    int s = 0;
    #pragma unroll
    for (int j = 0; j < 16; j++) s += h[j];
    cs[tid] = s; orig[tid] = s;
    __syncthreads();
    for (int off = 1; off < 256; off <<= 1){
      int v = (tid + off < 256) ? cs[tid + off] : 0;
      __syncthreads();
      cs[tid] += v;
      __syncthreads();
    }
    if (cs[tid] >= nums && (cs[tid] - orig[tid]) < nums){
      selc = tid; selrk = nums - (cs[tid] - orig[tid]);
    }
    __syncthreads();
    if (tid == 0){
      int ch = selc, rk = selrk;
      const int* hh = hist + e * 4096 + ch * 16;
      int acc = 0;
      for (int j = 15; j >= 0; j--){
        int c = hh[j];
        if (acc + c >= rk){ params[6 + e] = ch * 16 + j; params[9 + e] = rk - acc; break; }
        acc += c;
      }
    }
    __syncthreads();
  }
}

// ---------------------------------------------------------------------------
// level2hist: 2048-bin histogram (mantissa bits [10:0]) within chosen bucket.
// ---------------------------------------------------------------------------
__global__ void level2hist(const int* __restrict__ params, const unsigned int* __restrict__ wkey,
                           const unsigned char* __restrict__ mask3, int* __restrict__ h2)
{
  const int e = blockIdx.y;
  const int B = params[6 + e];
  if (B < 0) return;
  const unsigned char bit = (unsigned char)(1u << e);
  const int t0 = blockIdx.x * 2048 + threadIdx.x;
  #pragma unroll
  for (int i = 0; i < 8; i++){
    int t = t0 + i * 256;
    if (mask3[t] & bit){
      unsigned int u = wkey[t];
      if ((int)((u >> 11) & 0xFFFu) == B) atomicAdd(&h2[e * 2048 + (u & 2047u)], 1);
    }
  }
}

// ---------------------------------------------------------------------------
// find_theta: exact 23-bit threshold key, ties-to-take r, tie count c_eq.
// ---------------------------------------------------------------------------
__global__ void find_theta(int* __restrict__ params, const int* __restrict__ h2)
{
  const int e = blockIdx.x;
  const int tid = threadIdx.x;
  __shared__ int cs[256], orig[256];
  __shared__ int selc;
  int B = params[6 + e], rank = params[9 + e];
  if (B < 0){
    if (tid == 0){ params[12 + e] = (int)0xFFFFFFFFu; params[15 + e] = 0; params[18 + e] = 0; }
    return;
  }
  const int* h = h2 + e * 2048 + tid * 8;
  int s = 0;
  #pragma unroll
  for (int j = 0; j < 8; j++) s += h[j];
  cs[tid] = s; orig[tid] = s;
  __syncthreads();
  for (int off = 1; off < 256; off <<= 1){
    int v = (tid + off < 256) ? cs[tid + off] : 0;
    __syncthreads();
    cs[tid] += v;
    __syncthreads();
  }
  if (cs[tid] >= rank && (cs[tid] - orig[tid]) < rank) selc = tid;
  __syncthreads();
  if (tid == 0){
    int ch = selc;
    int rk = rank - (cs[ch] - orig[ch]);
    const int* hh = h2 + e * 2048 + ch * 8;
    int acc = 0;
    for (int j = 7; j >= 0; j--){
      int c = hh[j];
      if (acc + c >= rk){
        int sub = ch * 8 + j;
        params[12 + e] = (int)(0x3F000000u | ((unsigned)B << 11) | (unsigned)sub);
        params[15 + e] = rk - acc;
        params[18 + e] = c;
        break;
      }
      acc += c;
    }
  }
}

// ---------------------------------------------------------------------------
// mark_sel: sel = mask & key>theta; tokens with key==theta pushed to eqlist.
// ---------------------------------------------------------------------------
__global__ void mark_sel(int* __restrict__ params, const unsigned int* __restrict__ wkey,
                         const unsigned char* __restrict__ mask3, unsigned char* __restrict__ selb,
                         int* __restrict__ eqlist)
{
  const int e = blockIdx.y;
  const int bx = blockIdx.x;
  const int tid = threadIdx.x;
  const unsigned int theta = (unsigned int)params[12 + e];
  const unsigned char bit = (unsigned char)(1u << e);
  unsigned char* sb = selb + e * T_TOK;
  const int t0 = bx * 2048;
  #pragma unroll
  for (int i = 0; i < 8; i++){
    int t = t0 + i * 256 + tid;
    unsigned char mk = mask3[t] & bit;
    unsigned int u = wkey[t];
    sb[t] = (mk && u > theta) ? 1 : 0;
    if (mk && u == theta){
      int p = atomicAdd(&params[22 + e], 1);
      if (p < EQCAP) eqlist[e * EQCAP + p] = t;
    }
  }
}

// ---------------------------------------------------------------------------
// fix_ties: take the r ties with smallest token index (stable argsort match).
// ne is tiny in practice (key collisions at the exact threshold).
// ---------------------------------------------------------------------------
__global__ void fix_ties(const int* __restrict__ params, const int* __restrict__ eqlist,
                         unsigned char* __restrict__ selb)
{
  const int e = blockIdx.x;
  const int tid = threadIdx.x;
  const int r = params[15 + e];
  int ne = params[22 + e];
  if (ne > EQCAP) ne = EQCAP;
  unsigned char* sb = selb + e * T_TOK;
  const int* lst = eqlist + e * EQCAP;
  if (ne <= r){
    for (int i = tid; i < ne; i += 256) sb[lst[i]] = 1;
  } else {
    for (int i = tid; i < ne; i += 256){
      int ti = lst[i];
      int rank = 0;
      for (int j = 0; j < ne; j++) rank += (lst[j] < ti);
      if (rank < r) sb[ti] = 1;
    }
  }
}

// ---------------------------------------------------------------------------
// compact: tokens with total_sel>0 + multiplicity weight; count in params[21].
// ---------------------------------------------------------------------------
__global__ void compact(const unsigned char* __restrict__ selb, int* __restrict__ cidx,
                        float* __restrict__ wgt, int* __restrict__ params)
{
  int t = blockIdx.x * 256 + threadIdx.x;
  int ts = selb[t] + selb[T_TOK + t] + selb[2 * T_TOK + t];
  int lane = threadIdx.x & 63;
  unsigned long long bal = __ballot(ts > 0);
  int base = 0;
  if (lane == 0) base = atomicAdd(&params[21], __popcll(bal));
  base = __shfl(base, 0);
  if (ts){
    int pos = base + __popcll(bal & ((1ull << lane) - 1ull));
    cidx[pos] = t;
    wgt[pos] = (float)ts;
  }
}

// ---------------------------------------------------------------------------
// meanfeat_c: column sums of (bf16) patches over sel0/sel1 rows.
// ---------------------------------------------------------------------------
__global__ void meanfeat_c(const unsigned short* __restrict__ Ptch,
                           const unsigned char* __restrict__ selb,
                           const int* __restrict__ cidx, const int* __restrict__ params,
                           float* __restrict__ mf)
{
  const int count = params[21];
  const int base = blockIdx.x * 256;
  if (base >= count) return;
  const int n = min(256, count - base);
  const int tid = threadIdx.x;
  __shared__ int cl[256];
  __shared__ unsigned char f0s[256], f1s[256];
  if (tid < n){
    int c = cidx[base + tid];
    cl[tid] = c;
    f0s[tid] = selb[c];
    f1s[tid] = selb[T_TOK + c];
  }
  __syncthreads();
  float s00 = 0, s01 = 0, s10 = 0, s11 = 0;
  for (int i = 0; i < n; i++){
    int f0 = f0s[i], f1 = f1s[i];
    if (f0 | f1){
      unsigned int u = *(const unsigned int*)(Ptch + (size_t)cl[i] * PDIM + tid * 2);
      float vx = bf2f((unsigned short)(u & 0xFFFFu));
      float vy = bf2f((unsigned short)(u >> 16));
      if (f0){ s00 += vx; s01 += vy; }
      if (f1){ s10 += vx; s11 += vy; }
    }
  }
  atomicAdd(&mf[tid * 2],           s00);
  atomicAdd(&mf[tid * 2 + 1],       s01);
  atomicAdd(&mf[512 + tid * 2],     s10);
  atomicAdd(&mf[512 + tid * 2 + 1], s11);
}

// ---------------------------------------------------------------------------
// gemm_agg: agg column sums = sum_rows w(row) * tanh(patches[row] @ W_a1).
// ---------------------------------------------------------------------------
__global__ __launch_bounds__(256, 4)
void gemm_agg(const unsigned short* __restrict__ Ptch,
              const unsigned short* __restrict__ Bhg,
              float* __restrict__ aggsum,
              const int* __restrict__ cidx,
              const float* __restrict__ wgt,
              const int* __restrict__ params)
{
  __shared__ __align__(16) unsigned short Ah[4096];
  __shared__ __align__(16) unsigned short Bh[4096];
  __shared__ int   cidxl[128];
  __shared__ float wl[128];

  const int tid = threadIdx.x;
  int m_idx, nb;
  remap(blockIdx.y * 4 + blockIdx.x, m_idx, nb);
  const int m0 = m_idx * 128;
  const int n0 = nb * 128;
  const int count = params[21];
  if (m0 >= count) return;
  if (tid < 128){
    int gi = m0 + tid;
    if (gi < count){ cidxl[tid] = cidx[gi]; wl[tid] = wgt[gi]; }
    else           { cidxl[tid] = 0;        wl[tid] = 0.f;    }
  }
  __syncthreads();

  const int lane = tid & 63;
  const int wv   = tid >> 6;
  const int wm   = (wv & 1) << 6;
  const int wn   = (wv >> 1) << 6;
  const int lr   = lane & 15;
  const int quad = lane >> 4;

  const int ar = tid >> 2;
  const int aq = tid & 3;

  floatx4 acc[4][4];
  #pragma unroll
  for (int i = 0; i < 4; i++)
    #pragma unroll
    for (int j = 0; j < 4; j++)
      acc[i][j] = (floatx4){0.f, 0.f, 0.f, 0.f};

  for (int kb = 0; kb < 16; ++kb){
    const int k0 = kb << 5;
    #pragma unroll
    for (int it = 0; it < 2; it++){
      const int row = ar + it * 64;
      ushortx8 v = *(const ushortx8*)(Ptch + (size_t)cidxl[row] * PDIM + k0 + aq * 8);
      *(ushortx8*)&Ah[lds_off(row, aq)] = v;
      ushortx8 bv = *(const ushortx8*)(Bhg + (size_t)(n0 + row) * PDIM + k0 + aq * 8);
      *(ushortx8*)&Bh[lds_off(row, aq)] = bv;
    }
    __syncthreads();
    shortx8 a0[4], b0[4];
    #pragma unroll
    for (int i = 0; i < 4; i++){
      a0[i] = *(const shortx8*)&Ah[lds_off(wm + i * 16 + lr, quad)];
      b0[i] = *(const shortx8*)&Bh[lds_off(wn + i * 16 + lr, quad)];
    }
    #pragma unroll
    for (int i = 0; i < 4; i++)
      #pragma unroll
      for (int j = 0; j < 4; j++)
        acc[i][j] = __builtin_amdgcn_mfma_f32_16x16x32_bf16(a0[i], b0[j], acc[i][j], 0, 0, 0);
    __syncthreads();
  }

  float csum[4] = {0.f, 0.f, 0.f, 0.f};
  #pragma unroll
  for (int i = 0; i < 4; i++){
    const float4 wv4 = *(const float4*)&wl[wm + i * 16 + (quad << 2)];
    #pragma unroll
    for (int j = 0; j < 4; j++){
      csum[j] += ftanh(acc[i][j][0]) * wv4.x + ftanh(acc[i][j][1]) * wv4.y
               + ftanh(acc[i][j][2]) * wv4.z + ftanh(acc[i][j][3]) * wv4.w;
    }
  }
  #pragma unroll
  for (int j = 0; j < 4; j++){
    float sJ = csum[j];
    sJ += __shfl_xor(sJ, 16);
    sJ += __shfl_xor(sJ, 32);
    if (lane < 16) atomicAdd(&aggsum[n0 + wn + j * 16 + lane], sJ);
  }
}

// ---------------------------------------------------------------------------
// finalize: all small outputs.
// d_out: [0,2) e_Y_logits | [2] e_Y_hat | [3,5) Y_logits | [5,7) Y_prob |
//        [7] Y_hat | [8,131080) router_logits | [131080] joint | [131081,85) distribute
// ---------------------------------------------------------------------------
__global__ void finalize(const float* __restrict__ bagsum, const float* __restrict__ aggsum,
                         const float* __restrict__ mf, const int* __restrict__ params,
                         const float* __restrict__ Wcls1, const float* __restrict__ Wclf,
                         const float* __restrict__ Wacls, float* __restrict__ dout)
{
  const int lane = threadIdx.x;  // 64 threads
  const int nums0 = params[3], nums1 = params[4], nums2 = params[5];
  const float invT = 1.0f / 65536.0f;
  const float inv0 = 1.0f / (float)(nums0 > 0 ? nums0 : 1);
  const float inv1 = 1.0f / (float)(nums1 > 0 ? nums1 : 1);
  const float totn = (float)(nums0 + nums1 + nums2);
  const float invA = 1.0f / fmaxf(totn, 1.0f);
  float y0 = 0, y1 = 0, a0 = 0, a1 = 0;
  float l00 = 0, l01 = 0, l02 = 0, l10 = 0, l11 = 0, l12 = 0;
  #pragma unroll
  for (int j = 0; j < 8; j++){
    int p = lane * 8 + j;
    float bg = bagsum[p] * invT;
    y0 += bg * Wcls1[p * 2]; y1 += bg * Wcls1[p * 2 + 1];
    float ag = aggsum[p] * invA;
    a0 += ag * Wacls[p * 2]; a1 += ag * Wacls[p * 2 + 1];
    float m0v = mf[p] * inv0;
    l00 += m0v * Wclf[p * 3]; l01 += m0v * Wclf[p * 3 + 1]; l02 += m0v * Wclf[p * 3 + 2];
    float m1v = mf[512 + p] * inv1;
    l10 += m1v * Wclf[1536 + p * 3]; l11 += m1v * Wclf[1536 + p * 3 + 1]; l12 += m1v * Wclf[1536 + p * 3 + 2];
  }
  #pragma unroll
  for (int off = 1; off < 64; off <<= 1){
    y0 += __shfl_xor(y0, off);   y1 += __shfl_xor(y1, off);
    a0 += __shfl_xor(a0, off);   a1 += __shfl_xor(a1, off);
    l00 += __shfl_xor(l00, off); l01 += __shfl_xor(l01, off); l02 += __shfl_xor(l02, off);
    l10 += __shfl_xor(l10, off); l11 += __shfl_xor(l11, off); l12 += __shfl_xor(l12, off);
  }
  if (lane == 0){
    dout[0] = a0; dout[1] = a1;
    dout[2] = (a1 > a0) ? 1.0f : 0.0f;
    dout[3] = y0; dout[4] = y1;
    float mx = fmaxf(y0, y1), e0 = expf(y0 - mx), e1 = expf(y1 - mx), inv = 1.0f / (e0 + e1);
    dout[5] = e0 * inv; dout[6] = e1 * inv;
    dout[7] = (y1 > y0) ? 1.0f : 0.0f;
    float m3 = fmaxf(fmaxf(l00, l01), l02);
    float lse0 = m3 + logf(expf(l00 - m3) + expf(l01 - m3) + expf(l02 - m3));
    float m4 = fmaxf(fmaxf(l10, l11), l12);
    float lse1 = m4 + logf(expf(l10 - m4) + expf(l11 - m4) + expf(l12 - m4));
    dout[131080] = (lse0 - l00) + (lse1 - l11);
    dout[131081] = 65536.0f;
    dout[131082] = (float)nums0;
    dout[131083] = (float)nums1;
    dout[131084] = (float)nums2;
  }
}

// ---------------------------------------------------------------------------
extern "C" void kernel_launch(void* const* d_in, const int* in_sizes, int n_in,
                              void* d_out, int out_size, void* d_ws, size_t ws_size,
                              hipStream_t stream)
{
  const float* X      = (const float*)d_in[0];
  const float* W_t1   = (const float*)d_in[1];
  const float* W_cls1 = (const float*)d_in[2];
  const float* Wg0    = (const float*)d_in[3];
  const float* Wg1    = (const float*)d_in[4];
  const float* Wg2    = (const float*)d_in[5];
  const float* W_clf  = (const float*)d_in[6];
  const float* W_a1   = (const float*)d_in[7];
  const float* W_acls = (const float*)d_in[8];
  float* dout = (float*)d_out;
  char* ws = (char*)d_ws;

  // workspace layout (bytes)
  unsigned short* Ptch   = (unsigned short*)(ws + 0);           // 67108864
  unsigned short* W1th   = (unsigned short*)(ws + 67108864);    // 1048576
  unsigned short* W1tl   = (unsigned short*)(ws + 68157440);    // 1048576
  unsigned short* Wath   = (unsigned short*)(ws + 69206016);    // 524288
  unsigned int*   wkey   = (unsigned int*)  (ws + 69730304);    // 262144
  unsigned char*  mask3  = (unsigned char*) (ws + 69992448);    // 65536
  unsigned char*  selb   = (unsigned char*) (ws + 70057984);    // 196608
  int*            cidx   = (int*)           (ws + 70254592);    // 262144
  float*          wgt    = (float*)         (ws + 70516736);    // 262144
  float*          glogp  = (float*)         (ws + 70778880);    // 6291456 (4*T*6*4)
  int*            eqlist = (int*)           (ws + 77070336);    // 98304 (3*8192*4)
  int*            zbase  = (int*)           (ws + 77168640);    // 20544*4 zeroed
  int*   hist   = zbase;                                        // 3*4096
  int*   h2     = zbase + 12288;                                // 3*2048
  int*   params = zbase + 18432;                                // 64
  float* bagsum = (float*)(zbase + 18496);                      // 512
  float* aggsum = (float*)(zbase + 19008);                      // 512
  float* mf     = (float*)(zbase + 19520);                      // 1024 (end 20544)

  prep<<<213, 256, 0, stream>>>(W_t1, W_a1, W1th, W1tl, Wath, zbase);

  gemm_main<<<dim3(4, 512), 256, 0, stream>>>(
      X, W1th, W1tl, Ptch, bagsum, glogp, Wg0, Wg1, Wg2);

  gates_small<<<256, 256, 0, stream>>>(glogp, dout, wkey, mask3, params, hist);

  find_bucket<<<1, 256, 0, stream>>>(params, hist);
  level2hist<<<dim3(32, 3), 256, 0, stream>>>(params, wkey, mask3, h2);
  find_theta<<<3, 256, 0, stream>>>(params, h2);
  mark_sel<<<dim3(32, 3), 256, 0, stream>>>(params, wkey, mask3, selb, eqlist);
  fix_ties<<<3, 256, 0, stream>>>(params, eqlist, selb);
  compact<<<256, 256, 0, stream>>>(selb, cidx, wgt, params);

  meanfeat_c<<<256, 256, 0, stream>>>(Ptch, selb, cidx, params, mf);

  gemm_agg<<<dim3(4, 512), 256, 0, stream>>>(Ptch, Wath, aggsum, cidx, wgt, params);

  finalize<<<1, 64, 0, stream>>>(bagsum, aggsum, mf, params, W_cls1, W_clf, W_acls, dout);
}